// Round 5
// baseline (2395.288 us; speedup 1.0000x reference)
//
#include <hip/hip_runtime.h>
#include <math.h>

#define G_N 2048
#define CCH 256
#define PSTR 12   // {u,v,A,B,C,op,pthr,gid, rx,ry, pad,pad}
#define NBLK 1024
#define WC (64 * 64 * 9)

typedef short bhalf8 __attribute__((ext_vector_type(8)));
typedef float f32x4 __attribute__((ext_vector_type(4)));

__device__ __forceinline__ unsigned short f2bf(float f) {
    unsigned u = __float_as_uint(f);
    unsigned r = (u + 0x7fffu + ((u >> 16) & 1u)) >> 16;
    return (unsigned short)r;
}

// ---------------------------------------------------------------------------
// Device-scope grid barrier for the persistent kernel. Requires all NBLK
// blocks co-resident (guaranteed: LDS 25.6KB -> 4/CU of 160KB, VGPR<=128 via
// __launch_bounds__(256,4), 16 waves/CU of 32). __threadfence at agent scope
// emits the L2 writeback/invalidate needed across non-coherent XCD L2s.
// ---------------------------------------------------------------------------
__device__ __forceinline__ void gbar(int* bar, int target) {
    __threadfence();          // drain own stores + L2 writeback (release)
    __syncthreads();          // all waves of block flushed
    if (threadIdx.x == 0) {
        atomicAdd(bar, 1);    // device-scope
        while (__hip_atomic_load(bar, __ATOMIC_RELAXED, __HIP_MEMORY_SCOPE_AGENT) < target)
            __builtin_amdgcn_s_sleep(2);
    }
    __syncthreads();
    __threadfence();          // invalidate stale caches (acquire)
}

// ---------------------------------------------------------------------------
// Init launch: weight repack (blocks 0..197), splat precompute (198,199),
// zero barrier counter + stats accumulators (200).
// wprep layout: [c][pair(18)][m_tile(4)][lane(64)][j(8)] bf16
// ---------------------------------------------------------------------------
__global__ void gls_init(const float* __restrict__ conv1_w,
                         const float* __restrict__ blk_w,
                         const float* __restrict__ up_w,
                         unsigned short* __restrict__ wprep,
                         const float* __restrict__ means,
                         const float* __restrict__ cov6,
                         const float* __restrict__ opac,
                         float* __restrict__ params,
                         int* __restrict__ counts,
                         int* __restrict__ bar,
                         float* __restrict__ sacc)
{
    int bx = blockIdx.x;
    int tid = threadIdx.x;
    if (bx == 200) {
        if (tid == 0) *bar = 0;
        if (tid < 128) sacc[tid] = 0.f;
        return;
    }
    if (bx < 198) {
        int p = bx % 18, c = bx / 18;
        const float* src;
        if (c == 0) src = conv1_w;
        else if (c <= 4) src = blk_w + (c - 1) * WC;
        else if (c == 5) src = conv1_w + WC;
        else if (c == 6) src = up_w;
        else src = blk_w + (c - 3) * WC;
        int tap = p >> 1;
        int m = tid >> 6, lane = tid & 63;
        int oc = m * 16 + (lane & 15);
        int ci0 = (p & 1) * 32 + (lane >> 4) * 8;
        unsigned short v[8];
#pragma unroll
        for (int j = 0; j < 8; ++j)
            v[j] = f2bf(src[(oc * 64 + ci0 + j) * 9 + tap]);
        unsigned short* dst = wprep + ((c * 18 + p) * 4 + m) * 64 * 8 + lane * 8;
#pragma unroll
        for (int j = 0; j < 8; ++j) dst[j] = v[j];
        return;
    }
    // ---- precompute with order-preserving compaction ----
    int s = bx - 198;
    __shared__ int s_base;
    __shared__ int s_wsum[4];
    if (tid == 0) s_base = 0;
    __syncthreads();
    float* P = params + s * G_N * PSTR;
    float H = (float)(100 << s);
    float sh = (float)(1 << s);
    for (int it = 0; it < G_N / 256; ++it) {
        int g = it * 256 + tid;
        float mx = means[g * 3 + 0], my = means[g * 3 + 1], mz = means[g * 3 + 2];
        float op = opac[g * 2 + s];
        bool mask = (mx >= -50.f && mx <= 50.f && my >= -50.f && my <= 50.f &&
                     mz >= -4.f && mz <= 4.f && op > 0.05f);
        unsigned long long bal = __ballot(mask);
        int lane = tid & 63, wid = tid >> 6;
        int prefix = __popcll(bal & ((1ull << lane) - 1ull));
        if (lane == 0) s_wsum[wid] = __popcll(bal);
        __syncthreads();
        int woff = 0;
        for (int w = 0; w < 4; ++w) if (w < wid) woff += s_wsum[w];
        int pos = s_base + woff + prefix;
        if (mask) {
            float u = -sh * my + 0.5f * H;
            float v = -sh * mx + 0.5f * H;
            float a = sh * sh * cov6[g * 6 + 3] + 0.3f;
            float c = sh * sh * cov6[g * 6 + 0] + 0.3f;
            float bb = sh * sh * cov6[g * 6 + 1];
            float det = fmaxf(a * c - bb * bb, 1e-8f);
            float t = logf(255.f * op);
            float* Q = P + pos * PSTR;
            Q[0] = u; Q[1] = v;
            Q[2] = c / det; Q[3] = -bb / det; Q[4] = a / det;
            Q[5] = op; Q[6] = -t;
            Q[7] = __int_as_float(g);
            Q[8] = sqrtf(2.f * t * a);
            Q[9] = sqrtf(2.f * t * c);
            Q[10] = 0.f; Q[11] = 0.f;
        }
        __syncthreads();
        if (tid == 0) s_base += s_wsum[0] + s_wsum[1] + s_wsum[2] + s_wsum[3];
        __syncthreads();
    }
    if (tid == 0) counts[s] = s_base;
}

// ---------------------------------------------------------------------------
// Render one 16x16 tile (unit: 0..48 -> stage0 7x7; 49..217 -> stage1 13x13).
// ---------------------------------------------------------------------------
__device__ __forceinline__ void render_tile(
    int unit, const float* __restrict__ params, const int* __restrict__ counts,
    const float* __restrict__ feats, float* __restrict__ out0,
    float* __restrict__ out1, char* smem)
{
    int s = (unit < 49) ? 0 : 1;
    int t = (s == 0) ? unit : unit - 49;
    int tw = (s == 0) ? 7 : 13;
    int bx = t % tw, by = t / tw;
    int H = 100 << s;
    const float* P = params + s * G_N * PSTR;
    float* out = s ? out1 : out0;
    int cnt = counts[s];

    float* raw = (float*)smem;                 // CCH*PSTR floats
    float* cmp = raw + CCH * PSTR;             // CCH*PSTR floats
    int* s_wsum = (int*)(smem + 24576);

    int tid = threadIdx.x;
    int px = bx * 16 + (tid & 15);
    int py = by * 16 + (tid >> 4);
    bool active = (px < H) && (py < H);
    float fx = (float)px, fy = (float)py;
    float tx0 = (float)(bx * 16);
    float tx1 = (float)min(H - 1, bx * 16 + 15);
    float ty0 = (float)(by * 16);
    float ty1 = (float)min(H - 1, by * 16 + 15);

    float acc[64];
#pragma unroll
    for (int d = 0; d < 64; ++d) acc[d] = 0.f;
    float T = 1.f;

    for (int base = 0; base < cnt; base += CCH) {
        int anyalive = __syncthreads_or((int)(active && T > 1e-6f));
        if (!anyalive) break;
        int n = min(CCH, cnt - base);
        for (int i = tid; i < n * 3; i += 256)
            ((float4*)raw)[i] = ((const float4*)(P + base * PSTR))[i];
        __syncthreads();
        bool pass = false;
        if (tid < n) {
            float u = raw[tid * PSTR + 0], v = raw[tid * PSTR + 1];
            float rx = raw[tid * PSTR + 8], ry = raw[tid * PSTR + 9];
            pass = (u + rx >= tx0) && (u - rx <= tx1) &&
                   (v + ry >= ty0) && (v - ry <= ty1);
        }
        unsigned long long bal = __ballot(pass);
        int lane = tid & 63, wid = tid >> 6;
        int prefix = __popcll(bal & ((1ull << lane) - 1ull));
        if (lane == 0) s_wsum[wid] = __popcll(bal);
        __syncthreads();
        int woff = 0;
        for (int w = 0; w < 4; ++w) if (w < wid) woff += s_wsum[w];
        if (pass) {
            float4* dst = (float4*)(cmp + (woff + prefix) * PSTR);
            const float4* src = (const float4*)(raw + tid * PSTR);
            dst[0] = src[0]; dst[1] = src[1]; dst[2] = src[2];
        }
        __syncthreads();
        int nc = s_wsum[0] + s_wsum[1] + s_wsum[2] + s_wsum[3];
        if (active && T > 1e-6f) {
            for (int j = 0; j < nc; ++j) {
                float4 q0 = *(const float4*)(cmp + j * PSTR);
                float4 q1 = *(const float4*)(cmp + j * PSTR + 4);
                float dx = q0.x - fx, dy = q0.y - fy;
                float power = -0.5f * (q0.z * dx * dx + q1.x * dy * dy) - q0.w * dx * dy;
                if (power <= 0.f && power >= q1.z) {
                    float alpha = fminf(q1.y * __expf(power), 0.99f);
                    float wgt = alpha * T;
                    const float* f = feats + __float_as_int(q1.w) * 64;
#pragma unroll
                    for (int d = 0; d < 64; ++d) acc[d] = fmaf(wgt, f[d], acc[d]);
                    T *= (1.f - alpha);
                }
            }
        }
    }
    if (active) {
#pragma unroll
        for (int d = 0; d < 64; ++d) out[(d * H + py) * H + px] = acc[d];
    }
}

// ---------------------------------------------------------------------------
// MFMA conv3x3 64->64 tile (8x8 px x 64 oc), bf16 MFMA, f32 accum.
// ups: bilinear 2x upsample fused into staging (in is H/2).
// nrm: staging applies instance-norm (from sraw sums) + skip add (nskip),
//      writes result to nout (for the later residual) and uses it as input.
// dostats: accumulate per-channel sum/sumsq of conv output into sacc.
// mode: 0 none, 1 relu, 2 relu(conv+add), 4 conv + bev_emb[(y*W+x)*64+c]
// ---------------------------------------------------------------------------
__device__ __forceinline__ void conv_tile(
    int bx, int H,
    const float* __restrict__ in, const unsigned short* __restrict__ wp,
    const float* __restrict__ add, float* __restrict__ out,
    int mode, int ups, int nrm, int dostats,
    const float* __restrict__ nskip, const float* __restrict__ sraw,
    float* __restrict__ nout, float* __restrict__ sacc,
    char* smem)
{
    unsigned short* xlds = (unsigned short*)smem;   // 14400 B
    float* nm  = (float*)(smem + 14464);            // [64] mean
    float* nr  = nm + 64;                           // [64] rstd
    float* red = nr + 64;                           // [4*128]

    int tid = threadIdx.x;
    int gw = (H + 7) >> 3;
    int by = bx / gw, bxx = bx - by * gw;
    int y0 = by * 8, x0 = bxx * 8;
    int w = tid >> 6, lane = tid & 63;
    int n = lane & 15, q = lane >> 4;

    if (nrm) {
        if (tid < 64) {
            float s = sraw[tid], s2 = sraw[64 + tid];
            float mean = s * (1.f / 40000.f);
            float var = s2 * (1.f / 40000.f) - mean * mean;
            nm[tid] = mean;
            nr[tid] = rsqrtf(var + 1e-5f);
        }
        __syncthreads();
    }

    size_t st = (size_t)H * H;
    for (int idx = tid; idx < 1600; idx += 256) {
        int ci4 = idx / 100;
        int pos = idx - ci4 * 100;
        int yy = pos / 10, xx = pos - yy * 10;
        int gy = y0 - 1 + yy, gx = x0 - 1 + xx;
        ushort4 v4 = {0, 0, 0, 0};
        if (gy >= 0 && gy < H && gx >= 0 && gx < H) {
            int ci = ci4 * 4;
            if (ups) {
                int Hh = H >> 1;
                int yi = gy >> 1, xi = gx >> 1;
                int yb = (gy & 1) ? min(yi + 1, Hh - 1) : max(yi - 1, 0);
                int xb = (gx & 1) ? min(xi + 1, Hh - 1) : max(xi - 1, 0);
                int i00 = yi * Hh + xi, i01 = yi * Hh + xb;
                int i10 = yb * Hh + xi, i11 = yb * Hh + xb;
                unsigned short rr[4];
#pragma unroll
                for (int k = 0; k < 4; ++k) {
                    const float* p = in + (size_t)(ci + k) * Hh * Hh;
                    rr[k] = f2bf(0.5625f * p[i00] + 0.1875f * p[i01]
                               + 0.1875f * p[i10] + 0.0625f * p[i11]);
                }
                v4.x = rr[0]; v4.y = rr[1]; v4.z = rr[2]; v4.w = rr[3];
            } else if (nrm) {
                int pix = gy * H + gx;
                unsigned short rr[4];
#pragma unroll
                for (int k = 0; k < 4; ++k) {
                    float v = (in[(ci + k) * st + pix] - nm[ci + k]) * nr[ci + k]
                            + nskip[(ci + k) * st + pix];
                    nout[(ci + k) * st + pix] = v;   // duplicate halo writes: same value
                    rr[k] = f2bf(v);
                }
                v4.x = rr[0]; v4.y = rr[1]; v4.z = rr[2]; v4.w = rr[3];
            } else {
                const float* p = in + (size_t)ci * st + gy * H + gx;
                v4.x = f2bf(p[0]);
                v4.y = f2bf(p[st]);
                v4.z = f2bf(p[2 * st]);
                v4.w = f2bf(p[3 * st]);
            }
        }
        *(ushort4*)&xlds[pos * 72 + ci4 * 4] = v4;
    }
    __syncthreads();

    f32x4 acc[4];
#pragma unroll
    for (int m = 0; m < 4; ++m) acc[m] = (f32x4){0.f, 0.f, 0.f, 0.f};
    const bhalf8* wp8 = (const bhalf8*)wp;
    int sy = 2 * w + (n >> 3), sx = n & 7;

    bhalf8 a0 = wp8[0 * 64 + lane];
    bhalf8 a1 = wp8[1 * 64 + lane];
    bhalf8 a2 = wp8[2 * 64 + lane];
    bhalf8 a3 = wp8[3 * 64 + lane];
    bhalf8 bb = *(const bhalf8*)&xlds[(sy * 10 + sx) * 72 + q * 8];

#pragma unroll 1
    for (int p = 0; p < 18; ++p) {
        bhalf8 na0, na1, na2, na3, nbb;
        if (p < 17) {
            int pn = p + 1;
            na0 = wp8[(pn * 4 + 0) * 64 + lane];
            na1 = wp8[(pn * 4 + 1) * 64 + lane];
            na2 = wp8[(pn * 4 + 2) * 64 + lane];
            na3 = wp8[(pn * 4 + 3) * 64 + lane];
            int tap = pn >> 1, ch = pn & 1;
            int dy = tap / 3, dx = tap - dy * 3;
            nbb = *(const bhalf8*)&xlds[((sy + dy) * 10 + sx + dx) * 72 + ch * 32 + q * 8];
        }
        acc[0] = __builtin_amdgcn_mfma_f32_16x16x32_bf16(a0, bb, acc[0], 0, 0, 0);
        acc[1] = __builtin_amdgcn_mfma_f32_16x16x32_bf16(a1, bb, acc[1], 0, 0, 0);
        acc[2] = __builtin_amdgcn_mfma_f32_16x16x32_bf16(a2, bb, acc[2], 0, 0, 0);
        acc[3] = __builtin_amdgcn_mfma_f32_16x16x32_bf16(a3, bb, acc[3], 0, 0, 0);
        a0 = na0; a1 = na1; a2 = na2; a3 = na3; bb = nbb;
    }

    int gy = y0 + sy, gx = x0 + sx;
    if (gy < H && gx < H) {
#pragma unroll
        for (int m = 0; m < 4; ++m)
#pragma unroll
            for (int r = 0; r < 4; ++r) {
                int oc = m * 16 + q * 4 + r;
                float v = acc[m][r];
                int idxo = (oc * H + gy) * H + gx;
                if (mode == 1) v = fmaxf(v, 0.f);
                else if (mode == 2) v = fmaxf(v + add[idxo], 0.f);
                else if (mode == 4) v = v + add[(gy * H + gx) * 64 + oc];
                out[idxo] = v;
            }
    }

    if (dostats) {
        // per-channel sums over this tile's 64 px: shuffle over 16-lane q-groups
#pragma unroll
        for (int m = 0; m < 4; ++m)
#pragma unroll
            for (int r = 0; r < 4; ++r) {
                float v = acc[m][r];
                float s = v, s2 = v * v;
#pragma unroll
                for (int d = 1; d < 16; d <<= 1) {
                    s += __shfl_xor(s, d, 64);
                    s2 += __shfl_xor(s2, d, 64);
                }
                if (n == 0) {
                    int oc = m * 16 + q * 4 + r;
                    red[w * 128 + oc] = s;
                    red[w * 128 + 64 + oc] = s2;
                }
            }
        __syncthreads();
        if (tid < 128) {
            float t = red[tid] + red[128 + tid] + red[256 + tid] + red[384 + tid];
            atomicAdd(&sacc[tid], t);
        }
    }
}

// ---------------------------------------------------------------------------
// Persistent megakernel: 11 phases, 10 device-scope grid barriers.
// ---------------------------------------------------------------------------
__global__ __launch_bounds__(256, 4) void gls_mega(
    const float* __restrict__ feats, const float* __restrict__ bev_emb,
    const unsigned short* __restrict__ wprep,
    const float* __restrict__ params, const int* __restrict__ cnts,
    float* __restrict__ R0, float* __restrict__ A0,
    float* __restrict__ T0, float* __restrict__ B0,
    float* __restrict__ Q0, float* __restrict__ Q1,
    float* __restrict__ Q2, float* __restrict__ Q3,
    float* __restrict__ out, int* __restrict__ bar, float* __restrict__ sacc)
{
    __shared__ __align__(16) char smem[25600];
    int bid = blockIdx.x;
    int tgt = 0;

    // P1: render both stages (218 tiles)
    if (bid < 218) render_tile(bid, params, cnts, feats, R0, Q0, smem);
    gbar(bar, tgt += NBLK);

    // P2: c0 (H100, +bev_emb) concurrent with c5 (H200 skip conv)
    if (bid < 169)
        conv_tile(bid, 100, R0, wprep + 0 * WC, bev_emb, A0, 4, 0, 0, 0,
                  nullptr, nullptr, nullptr, nullptr, smem);
    else if (bid < 794)
        conv_tile(bid - 169, 200, Q0, wprep + 5 * WC, nullptr, Q1, 0, 0, 0, 0,
                  nullptr, nullptr, nullptr, nullptr, smem);
    gbar(bar, tgt += NBLK);

    // P3..P6: H100 basic blocks
    if (bid < 169)
        conv_tile(bid, 100, A0, wprep + 1 * WC, nullptr, T0, 1, 0, 0, 0,
                  nullptr, nullptr, nullptr, nullptr, smem);
    gbar(bar, tgt += NBLK);
    if (bid < 169)
        conv_tile(bid, 100, T0, wprep + 2 * WC, A0, B0, 2, 0, 0, 0,
                  nullptr, nullptr, nullptr, nullptr, smem);
    gbar(bar, tgt += NBLK);
    if (bid < 169)
        conv_tile(bid, 100, B0, wprep + 3 * WC, nullptr, T0, 1, 0, 0, 0,
                  nullptr, nullptr, nullptr, nullptr, smem);
    gbar(bar, tgt += NBLK);
    if (bid < 169)
        conv_tile(bid, 100, T0, wprep + 4 * WC, B0, A0, 2, 0, 0, 0,
                  nullptr, nullptr, nullptr, nullptr, smem);
    gbar(bar, tgt += NBLK);

    // P7: upconv (fused bilinear upsample) + instance-norm stats accumulation
    if (bid < 625)
        conv_tile(bid, 200, A0, wprep + 6 * WC, nullptr, Q3, 0, 1, 0, 1,
                  nullptr, nullptr, nullptr, sacc, smem);
    gbar(bar, tgt += NBLK);

    // P8: c7 with fused instance-norm + skip-add staging (materializes Q0)
    if (bid < 625)
        conv_tile(bid, 200, Q3, wprep + 7 * WC, nullptr, Q2, 1, 0, 1, 0,
                  Q1, sacc, Q0, nullptr, smem);
    gbar(bar, tgt += NBLK);

    // P9..P11: H200 basic blocks, final conv writes d_out
    if (bid < 625)
        conv_tile(bid, 200, Q2, wprep + 8 * WC, Q0, Q1, 2, 0, 0, 0,
                  nullptr, nullptr, nullptr, nullptr, smem);
    gbar(bar, tgt += NBLK);
    if (bid < 625)
        conv_tile(bid, 200, Q1, wprep + 9 * WC, nullptr, Q2, 1, 0, 0, 0,
                  nullptr, nullptr, nullptr, nullptr, smem);
    gbar(bar, tgt += NBLK);
    if (bid == 0 && threadIdx.x == 0)
        out[2560000] = (float)(cnts[0] + cnts[1]);
    if (bid < 625)
        conv_tile(bid, 200, Q2, wprep + 10 * WC, Q1, out, 2, 0, 0, 0,
                  nullptr, nullptr, nullptr, nullptr, smem);
}

// ---------------------------------------------------------------------------
extern "C" void kernel_launch(void* const* d_in, const int* in_sizes, int n_in,
                              void* d_out, int out_size, void* d_ws, size_t ws_size,
                              hipStream_t stream)
{
    const float* feats   = (const float*)d_in[0];
    const float* means   = (const float*)d_in[1];
    const float* cov6    = (const float*)d_in[2];
    const float* opac    = (const float*)d_in[3];
    const float* bev_emb = (const float*)d_in[4];
    const float* conv1_w = (const float*)d_in[5];
    const float* blk_w   = (const float*)d_in[6];
    const float* up_w    = (const float*)d_in[7];
    float* out = (float*)d_out;
    float* ws = (float*)d_ws;

    float* P     = ws;                          // 49152 floats
    int*   cnts  = (int*)(ws + 49152);          // 2 ints
    int*   bar   = (int*)(ws + 49216);          // barrier counter
    float* sacc  = ws + 49280;                  // 128 floats (sum/sumsq)
    unsigned short* wprep = (unsigned short*)(ws + 49664);  // 11*36864 u16
    float* R0 = ws + 262144;                    // 640000 (H=100 buffers)
    float* A0 = ws + 917504;
    float* T0 = ws + 1572864;
    float* B0 = ws + 2228224;
    float* Q0 = ws + 2883584;                   // 2560000 (H=200 buffers)
    float* Q1 = ws + 5505024;
    float* Q2 = ws + 8126464;
    float* Q3 = ws + 10747904;

    gls_init<<<201, 256, 0, stream>>>(conv1_w, blk_w, up_w, wprep,
                                      means, cov6, opac, P, cnts, bar, sacc);
    gls_mega<<<NBLK, 256, 0, stream>>>(feats, bev_emb, wprep, P, cnts,
                                       R0, A0, T0, B0, Q0, Q1, Q2, Q3,
                                       out, bar, sacc);
    (void)in_sizes; (void)n_in; (void)out_size; (void)ws_size;
}

// Round 6
// 384.417 us; speedup vs baseline: 6.2310x; 6.2310x over previous
//
#include <hip/hip_runtime.h>
#include <math.h>

#define G_N 2048
#define CCH 256
#define PSTR 12   // {u,v,A,B,C,op,pthr,gid, rx,ry, pad,pad}
#define NBLK 1024
#define WC (64 * 64 * 9)

typedef short bhalf8 __attribute__((ext_vector_type(8)));
typedef float f32x4 __attribute__((ext_vector_type(4)));

__device__ __forceinline__ unsigned short f2bf(float f) {
    unsigned u = __float_as_uint(f);
    unsigned r = (u + 0x7fffu + ((u >> 16) & 1u)) >> 16;
    return (unsigned short)r;
}

// Coherent (agent-scope, sc0 sc1: bypass L1+L2, served by memory-side IC)
// load/store for cross-phase activation data. No fence/wbl2 needed.
__device__ __forceinline__ float cload(const float* p) {
    return __hip_atomic_load(p, __ATOMIC_RELAXED, __HIP_MEMORY_SCOPE_AGENT);
}
__device__ __forceinline__ void cstore(float* p, float v) {
    __hip_atomic_store(p, v, __ATOMIC_RELAXED, __HIP_MEMORY_SCOPE_AGENT);
}

// ---------------------------------------------------------------------------
// Fence-free grid barrier: per-wave s_waitcnt drains coherent stores (they
// complete at the coherent point, so visibility is global once vmcnt=0);
// 2-level tree counter (32 groups of 32) cuts single-address atomic
// contention; monotonic targets, no reset. All NBLK blocks co-resident
// (verified: occupancy 49% = 16/32 waves/CU at 4 blocks/CU).
// ---------------------------------------------------------------------------
__device__ __forceinline__ void gbar(int* leaf, int* root, int* flag, int phase) {
    asm volatile("s_waitcnt vmcnt(0) lgkmcnt(0)" ::: "memory");
    __syncthreads();   // every wave has drained its stores
    if (threadIdx.x == 0) {
        int g = blockIdx.x >> 5;
        int old = atomicAdd(&leaf[g * 16], 1);          // device-scope
        if ((old & 31) == 31) {
            int o2 = atomicAdd(root, 1);
            if ((o2 & 31) == 31)
                __hip_atomic_store(flag, phase, __ATOMIC_RELAXED,
                                   __HIP_MEMORY_SCOPE_AGENT);
        }
        while (__hip_atomic_load(flag, __ATOMIC_RELAXED,
                                 __HIP_MEMORY_SCOPE_AGENT) < phase)
            __builtin_amdgcn_s_sleep(4);
    }
    __syncthreads();
    asm volatile("" ::: "memory");
}

// ---------------------------------------------------------------------------
// Init launch: weight repack (0..197), splat precompute (198,199),
// zero barrier counters + stats accumulators (200).
// wprep layout: [c][pair(18)][m_tile(4)][lane(64)][j(8)] bf16
// ---------------------------------------------------------------------------
__global__ void gls_init(const float* __restrict__ conv1_w,
                         const float* __restrict__ blk_w,
                         const float* __restrict__ up_w,
                         unsigned short* __restrict__ wprep,
                         const float* __restrict__ means,
                         const float* __restrict__ cov6,
                         const float* __restrict__ opac,
                         float* __restrict__ params,
                         int* __restrict__ counts,
                         int* __restrict__ barmem,
                         float* __restrict__ sacc)
{
    int bx = blockIdx.x;
    int tid = threadIdx.x;
    if (bx == 200) {
        for (int i = tid; i < 520; i += 256) barmem[i] = 0;  // leaf[512]+root+flag
        if (tid < 128) sacc[tid] = 0.f;
        return;
    }
    if (bx < 198) {
        int p = bx % 18, c = bx / 18;
        const float* src;
        if (c == 0) src = conv1_w;
        else if (c <= 4) src = blk_w + (c - 1) * WC;
        else if (c == 5) src = conv1_w + WC;
        else if (c == 6) src = up_w;
        else src = blk_w + (c - 3) * WC;
        int tap = p >> 1;
        int m = tid >> 6, lane = tid & 63;
        int oc = m * 16 + (lane & 15);
        int ci0 = (p & 1) * 32 + (lane >> 4) * 8;
        unsigned short v[8];
#pragma unroll
        for (int j = 0; j < 8; ++j)
            v[j] = f2bf(src[(oc * 64 + ci0 + j) * 9 + tap]);
        unsigned short* dst = wprep + ((c * 18 + p) * 4 + m) * 64 * 8 + lane * 8;
#pragma unroll
        for (int j = 0; j < 8; ++j) dst[j] = v[j];
        return;
    }
    // ---- precompute with order-preserving compaction ----
    int s = bx - 198;
    __shared__ int s_base;
    __shared__ int s_wsum[4];
    if (tid == 0) s_base = 0;
    __syncthreads();
    float* P = params + s * G_N * PSTR;
    float H = (float)(100 << s);
    float sh = (float)(1 << s);
    for (int it = 0; it < G_N / 256; ++it) {
        int g = it * 256 + tid;
        float mx = means[g * 3 + 0], my = means[g * 3 + 1], mz = means[g * 3 + 2];
        float op = opac[g * 2 + s];
        bool mask = (mx >= -50.f && mx <= 50.f && my >= -50.f && my <= 50.f &&
                     mz >= -4.f && mz <= 4.f && op > 0.05f);
        unsigned long long bal = __ballot(mask);
        int lane = tid & 63, wid = tid >> 6;
        int prefix = __popcll(bal & ((1ull << lane) - 1ull));
        if (lane == 0) s_wsum[wid] = __popcll(bal);
        __syncthreads();
        int woff = 0;
        for (int w = 0; w < 4; ++w) if (w < wid) woff += s_wsum[w];
        int pos = s_base + woff + prefix;
        if (mask) {
            float u = -sh * my + 0.5f * H;
            float v = -sh * mx + 0.5f * H;
            float a = sh * sh * cov6[g * 6 + 3] + 0.3f;
            float c = sh * sh * cov6[g * 6 + 0] + 0.3f;
            float bb = sh * sh * cov6[g * 6 + 1];
            float det = fmaxf(a * c - bb * bb, 1e-8f);
            float t = logf(255.f * op);
            float* Q = P + pos * PSTR;
            Q[0] = u; Q[1] = v;
            Q[2] = c / det; Q[3] = -bb / det; Q[4] = a / det;
            Q[5] = op; Q[6] = -t;
            Q[7] = __int_as_float(g);
            Q[8] = sqrtf(2.f * t * a);
            Q[9] = sqrtf(2.f * t * c);
            Q[10] = 0.f; Q[11] = 0.f;
        }
        __syncthreads();
        if (tid == 0) s_base += s_wsum[0] + s_wsum[1] + s_wsum[2] + s_wsum[3];
        __syncthreads();
    }
    if (tid == 0) counts[s] = s_base;
}

// ---------------------------------------------------------------------------
// Render one 16x16 tile (unit: 0..48 -> stage0 7x7; 49..217 -> stage1 13x13).
// params/feats are init-launch products (cached reads OK); output via cstore.
// ---------------------------------------------------------------------------
__device__ __forceinline__ void render_tile(
    int unit, const float* __restrict__ params, const int* __restrict__ counts,
    const float* __restrict__ feats, float* __restrict__ out0,
    float* __restrict__ out1, char* smem)
{
    int s = (unit < 49) ? 0 : 1;
    int t = (s == 0) ? unit : unit - 49;
    int tw = (s == 0) ? 7 : 13;
    int bx = t % tw, by = t / tw;
    int H = 100 << s;
    const float* P = params + s * G_N * PSTR;
    float* out = s ? out1 : out0;
    int cnt = counts[s];

    float* raw = (float*)smem;
    float* cmp = raw + CCH * PSTR;
    int* s_wsum = (int*)(smem + 24576);

    int tid = threadIdx.x;
    int px = bx * 16 + (tid & 15);
    int py = by * 16 + (tid >> 4);
    bool active = (px < H) && (py < H);
    float fx = (float)px, fy = (float)py;
    float tx0 = (float)(bx * 16);
    float tx1 = (float)min(H - 1, bx * 16 + 15);
    float ty0 = (float)(by * 16);
    float ty1 = (float)min(H - 1, by * 16 + 15);

    float acc[64];
#pragma unroll
    for (int d = 0; d < 64; ++d) acc[d] = 0.f;
    float T = 1.f;

    for (int base = 0; base < cnt; base += CCH) {
        int anyalive = __syncthreads_or((int)(active && T > 1e-6f));
        if (!anyalive) break;
        int n = min(CCH, cnt - base);
        for (int i = tid; i < n * 3; i += 256)
            ((float4*)raw)[i] = ((const float4*)(P + base * PSTR))[i];
        __syncthreads();
        bool pass = false;
        if (tid < n) {
            float u = raw[tid * PSTR + 0], v = raw[tid * PSTR + 1];
            float rx = raw[tid * PSTR + 8], ry = raw[tid * PSTR + 9];
            pass = (u + rx >= tx0) && (u - rx <= tx1) &&
                   (v + ry >= ty0) && (v - ry <= ty1);
        }
        unsigned long long bal = __ballot(pass);
        int lane = tid & 63, wid = tid >> 6;
        int prefix = __popcll(bal & ((1ull << lane) - 1ull));
        if (lane == 0) s_wsum[wid] = __popcll(bal);
        __syncthreads();
        int woff = 0;
        for (int w = 0; w < 4; ++w) if (w < wid) woff += s_wsum[w];
        if (pass) {
            float4* dst = (float4*)(cmp + (woff + prefix) * PSTR);
            const float4* src = (const float4*)(raw + tid * PSTR);
            dst[0] = src[0]; dst[1] = src[1]; dst[2] = src[2];
        }
        __syncthreads();
        int nc = s_wsum[0] + s_wsum[1] + s_wsum[2] + s_wsum[3];
        if (active && T > 1e-6f) {
            for (int j = 0; j < nc; ++j) {
                float4 q0 = *(const float4*)(cmp + j * PSTR);
                float4 q1 = *(const float4*)(cmp + j * PSTR + 4);
                float dx = q0.x - fx, dy = q0.y - fy;
                float power = -0.5f * (q0.z * dx * dx + q1.x * dy * dy) - q0.w * dx * dy;
                if (power <= 0.f && power >= q1.z) {
                    float alpha = fminf(q1.y * __expf(power), 0.99f);
                    float wgt = alpha * T;
                    const float* f = feats + __float_as_int(q1.w) * 64;
#pragma unroll
                    for (int d = 0; d < 64; ++d) acc[d] = fmaf(wgt, f[d], acc[d]);
                    T *= (1.f - alpha);
                }
            }
        }
    }
    if (active) {
#pragma unroll
        for (int d = 0; d < 64; ++d) cstore(&out[(d * H + py) * H + px], acc[d]);
    }
}

// ---------------------------------------------------------------------------
// MFMA conv3x3 tile. All activation traffic via cload/cstore (coherent).
// mode: 0 none, 1 relu, 2 relu(conv+add), 4 conv + bev_emb[(y*W+x)*64+c]
// ups: bilinear upsample fused in staging; nrm: instance-norm+skip staging.
// ---------------------------------------------------------------------------
__device__ __forceinline__ void conv_tile(
    int bx, int H,
    const float* __restrict__ in, const unsigned short* __restrict__ wp,
    const float* __restrict__ add, float* __restrict__ out,
    int mode, int ups, int nrm, int dostats,
    const float* __restrict__ nskip, const float* __restrict__ sraw,
    float* __restrict__ nout, float* __restrict__ sacc,
    char* smem)
{
    unsigned short* xlds = (unsigned short*)smem;   // 14400 B
    float* nm  = (float*)(smem + 14464);
    float* nr  = nm + 64;
    float* red = nr + 64;                           // [4*128]

    int tid = threadIdx.x;
    int gw = (H + 7) >> 3;
    int by = bx / gw, bxx = bx - by * gw;
    int y0 = by * 8, x0 = bxx * 8;
    int w = tid >> 6, lane = tid & 63;
    int n = lane & 15, q = lane >> 4;

    if (nrm) {
        if (tid < 64) {
            float s = cload(&sraw[tid]), s2 = cload(&sraw[64 + tid]);
            float mean = s * (1.f / 40000.f);
            float var = s2 * (1.f / 40000.f) - mean * mean;
            nm[tid] = mean;
            nr[tid] = rsqrtf(var + 1e-5f);
        }
        __syncthreads();
    }

    size_t st = (size_t)H * H;
    for (int idx = tid; idx < 1600; idx += 256) {
        int ci4 = idx / 100;
        int pos = idx - ci4 * 100;
        int yy = pos / 10, xx = pos - yy * 10;
        int gy = y0 - 1 + yy, gx = x0 - 1 + xx;
        ushort4 v4 = {0, 0, 0, 0};
        if (gy >= 0 && gy < H && gx >= 0 && gx < H) {
            int ci = ci4 * 4;
            if (ups) {
                int Hh = H >> 1;
                int yi = gy >> 1, xi = gx >> 1;
                int yb = (gy & 1) ? min(yi + 1, Hh - 1) : max(yi - 1, 0);
                int xb = (gx & 1) ? min(xi + 1, Hh - 1) : max(xi - 1, 0);
                int i00 = yi * Hh + xi, i01 = yi * Hh + xb;
                int i10 = yb * Hh + xi, i11 = yb * Hh + xb;
                unsigned short rr[4];
#pragma unroll
                for (int k = 0; k < 4; ++k) {
                    const float* p = in + (size_t)(ci + k) * Hh * Hh;
                    rr[k] = f2bf(0.5625f * cload(&p[i00]) + 0.1875f * cload(&p[i01])
                               + 0.1875f * cload(&p[i10]) + 0.0625f * cload(&p[i11]));
                }
                v4.x = rr[0]; v4.y = rr[1]; v4.z = rr[2]; v4.w = rr[3];
            } else if (nrm) {
                int pix = gy * H + gx;
                unsigned short rr[4];
#pragma unroll
                for (int k = 0; k < 4; ++k) {
                    float v = (cload(&in[(ci + k) * st + pix]) - nm[ci + k]) * nr[ci + k]
                            + cload(&nskip[(ci + k) * st + pix]);
                    cstore(&nout[(ci + k) * st + pix], v);  // halo dups: same value
                    rr[k] = f2bf(v);
                }
                v4.x = rr[0]; v4.y = rr[1]; v4.z = rr[2]; v4.w = rr[3];
            } else {
                const float* p = in + (size_t)ci * st + gy * H + gx;
                v4.x = f2bf(cload(&p[0]));
                v4.y = f2bf(cload(&p[st]));
                v4.z = f2bf(cload(&p[2 * st]));
                v4.w = f2bf(cload(&p[3 * st]));
            }
        }
        *(ushort4*)&xlds[pos * 72 + ci4 * 4] = v4;
    }
    __syncthreads();

    f32x4 acc[4];
#pragma unroll
    for (int m = 0; m < 4; ++m) acc[m] = (f32x4){0.f, 0.f, 0.f, 0.f};
    const bhalf8* wp8 = (const bhalf8*)wp;
    int sy = 2 * w + (n >> 3), sx = n & 7;

    bhalf8 a0 = wp8[0 * 64 + lane];
    bhalf8 a1 = wp8[1 * 64 + lane];
    bhalf8 a2 = wp8[2 * 64 + lane];
    bhalf8 a3 = wp8[3 * 64 + lane];
    bhalf8 bb = *(const bhalf8*)&xlds[(sy * 10 + sx) * 72 + q * 8];

#pragma unroll 1
    for (int p = 0; p < 18; ++p) {
        bhalf8 na0, na1, na2, na3, nbb;
        if (p < 17) {
            int pn = p + 1;
            na0 = wp8[(pn * 4 + 0) * 64 + lane];
            na1 = wp8[(pn * 4 + 1) * 64 + lane];
            na2 = wp8[(pn * 4 + 2) * 64 + lane];
            na3 = wp8[(pn * 4 + 3) * 64 + lane];
            int tap = pn >> 1, ch = pn & 1;
            int dy = tap / 3, dx = tap - dy * 3;
            nbb = *(const bhalf8*)&xlds[((sy + dy) * 10 + sx + dx) * 72 + ch * 32 + q * 8];
        }
        acc[0] = __builtin_amdgcn_mfma_f32_16x16x32_bf16(a0, bb, acc[0], 0, 0, 0);
        acc[1] = __builtin_amdgcn_mfma_f32_16x16x32_bf16(a1, bb, acc[1], 0, 0, 0);
        acc[2] = __builtin_amdgcn_mfma_f32_16x16x32_bf16(a2, bb, acc[2], 0, 0, 0);
        acc[3] = __builtin_amdgcn_mfma_f32_16x16x32_bf16(a3, bb, acc[3], 0, 0, 0);
        a0 = na0; a1 = na1; a2 = na2; a3 = na3; bb = nbb;
    }

    int gy = y0 + sy, gx = x0 + sx;
    if (gy < H && gx < H) {
#pragma unroll
        for (int m = 0; m < 4; ++m)
#pragma unroll
            for (int r = 0; r < 4; ++r) {
                int oc = m * 16 + q * 4 + r;
                float v = acc[m][r];
                int idxo = (oc * H + gy) * H + gx;
                if (mode == 1) v = fmaxf(v, 0.f);
                else if (mode == 2) v = fmaxf(v + cload(&add[idxo]), 0.f);
                else if (mode == 4) v = v + add[(gy * H + gx) * 64 + oc];  // bev_emb: input, cached
                cstore(&out[idxo], v);
            }
    }

    if (dostats) {
#pragma unroll
        for (int m = 0; m < 4; ++m)
#pragma unroll
            for (int r = 0; r < 4; ++r) {
                float v = acc[m][r];
                float s = v, s2 = v * v;
#pragma unroll
                for (int d = 1; d < 16; d <<= 1) {
                    s += __shfl_xor(s, d, 64);
                    s2 += __shfl_xor(s2, d, 64);
                }
                if (n == 0) {
                    int oc = m * 16 + q * 4 + r;
                    red[w * 128 + oc] = s;
                    red[w * 128 + 64 + oc] = s2;
                }
            }
        __syncthreads();
        if (tid < 128) {
            float t = red[tid] + red[128 + tid] + red[256 + tid] + red[384 + tid];
            atomicAdd(&sacc[tid], t);
        }
    }
}

// ---------------------------------------------------------------------------
// Persistent megakernel: 11 phases, 10 fence-free grid barriers.
// ---------------------------------------------------------------------------
__global__ __launch_bounds__(256, 4) void gls_mega(
    const float* __restrict__ feats, const float* __restrict__ bev_emb,
    const unsigned short* __restrict__ wprep,
    const float* __restrict__ params, const int* __restrict__ cnts,
    float* __restrict__ R0, float* __restrict__ A0,
    float* __restrict__ T0, float* __restrict__ B0,
    float* __restrict__ Q0, float* __restrict__ Q1,
    float* __restrict__ Q2, float* __restrict__ Q3,
    float* __restrict__ out, int* __restrict__ barmem, float* __restrict__ sacc)
{
    __shared__ __align__(16) char smem[25600];
    int bid = blockIdx.x;
    int* leaf = barmem;
    int* root = barmem + 512;
    int* flag = barmem + 513;
    int ph = 0;

    // P1: render both stages (218 tiles)
    if (bid < 218) render_tile(bid, params, cnts, feats, R0, Q0, smem);
    gbar(leaf, root, flag, ++ph);

    // P2: c0 (H100, +bev_emb) concurrent with c5 (H200 skip conv)
    if (bid < 169)
        conv_tile(bid, 100, R0, wprep + 0 * WC, bev_emb, A0, 4, 0, 0, 0,
                  nullptr, nullptr, nullptr, nullptr, smem);
    else if (bid < 794)
        conv_tile(bid - 169, 200, Q0, wprep + 5 * WC, nullptr, Q1, 0, 0, 0, 0,
                  nullptr, nullptr, nullptr, nullptr, smem);
    gbar(leaf, root, flag, ++ph);

    // P3..P6: H100 basic blocks
    if (bid < 169)
        conv_tile(bid, 100, A0, wprep + 1 * WC, nullptr, T0, 1, 0, 0, 0,
                  nullptr, nullptr, nullptr, nullptr, smem);
    gbar(leaf, root, flag, ++ph);
    if (bid < 169)
        conv_tile(bid, 100, T0, wprep + 2 * WC, A0, B0, 2, 0, 0, 0,
                  nullptr, nullptr, nullptr, nullptr, smem);
    gbar(leaf, root, flag, ++ph);
    if (bid < 169)
        conv_tile(bid, 100, B0, wprep + 3 * WC, nullptr, T0, 1, 0, 0, 0,
                  nullptr, nullptr, nullptr, nullptr, smem);
    gbar(leaf, root, flag, ++ph);
    if (bid < 169)
        conv_tile(bid, 100, T0, wprep + 4 * WC, B0, A0, 2, 0, 0, 0,
                  nullptr, nullptr, nullptr, nullptr, smem);
    gbar(leaf, root, flag, ++ph);

    // P7: upconv (fused bilinear upsample) + instance-norm stats
    if (bid < 625)
        conv_tile(bid, 200, A0, wprep + 6 * WC, nullptr, Q3, 0, 1, 0, 1,
                  nullptr, nullptr, nullptr, sacc, smem);
    gbar(leaf, root, flag, ++ph);

    // P8: c7 with fused instance-norm + skip-add staging (materializes Q0)
    if (bid < 625)
        conv_tile(bid, 200, Q3, wprep + 7 * WC, nullptr, Q2, 1, 0, 1, 0,
                  Q1, sacc, Q0, nullptr, smem);
    gbar(leaf, root, flag, ++ph);

    // P9..P11: H200 basic blocks, final conv writes d_out
    if (bid < 625)
        conv_tile(bid, 200, Q2, wprep + 8 * WC, Q0, Q1, 2, 0, 0, 0,
                  nullptr, nullptr, nullptr, nullptr, smem);
    gbar(leaf, root, flag, ++ph);
    if (bid < 625)
        conv_tile(bid, 200, Q1, wprep + 9 * WC, nullptr, Q2, 1, 0, 0, 0,
                  nullptr, nullptr, nullptr, nullptr, smem);
    gbar(leaf, root, flag, ++ph);
    if (bid == 0 && threadIdx.x == 0)
        cstore(&out[2560000], (float)(cnts[0] + cnts[1]));
    if (bid < 625)
        conv_tile(bid, 200, Q2, wprep + 10 * WC, Q1, out, 2, 0, 0, 0,
                  nullptr, nullptr, nullptr, nullptr, smem);
}

// ---------------------------------------------------------------------------
extern "C" void kernel_launch(void* const* d_in, const int* in_sizes, int n_in,
                              void* d_out, int out_size, void* d_ws, size_t ws_size,
                              hipStream_t stream)
{
    const float* feats   = (const float*)d_in[0];
    const float* means   = (const float*)d_in[1];
    const float* cov6    = (const float*)d_in[2];
    const float* opac    = (const float*)d_in[3];
    const float* bev_emb = (const float*)d_in[4];
    const float* conv1_w = (const float*)d_in[5];
    const float* blk_w   = (const float*)d_in[6];
    const float* up_w    = (const float*)d_in[7];
    float* out = (float*)d_out;
    float* ws = (float*)d_ws;

    float* P      = ws;                          // 49152 floats
    int*   cnts   = (int*)(ws + 49152);          // 2 ints
    int*   barmem = (int*)(ws + 49280);          // 520 ints (leaf512+root+flag)
    float* sacc   = ws + 49856;                  // 128 floats
    unsigned short* wprep = (unsigned short*)(ws + 50176);  // 11*36864 u16
    float* R0 = ws + 262144;                     // 640000 (H=100 buffers)
    float* A0 = ws + 917504;
    float* T0 = ws + 1572864;
    float* B0 = ws + 2228224;
    float* Q0 = ws + 2883584;                    // 2560000 (H=200 buffers)
    float* Q1 = ws + 5505024;
    float* Q2 = ws + 8126464;
    float* Q3 = ws + 10747904;

    gls_init<<<201, 256, 0, stream>>>(conv1_w, blk_w, up_w, wprep,
                                      means, cov6, opac, P, cnts, barmem, sacc);
    gls_mega<<<NBLK, 256, 0, stream>>>(feats, bev_emb, wprep, P, cnts,
                                       R0, A0, T0, B0, Q0, Q1, Q2, Q3,
                                       out, barmem, sacc);
    (void)in_sizes; (void)n_in; (void)out_size; (void)ws_size;
}

// Round 7
// 360.522 us; speedup vs baseline: 6.6439x; 1.0663x over previous
//
#include <hip/hip_runtime.h>
#include <math.h>

#define G_N 2048
#define CCH 256
#define PSTR 12   // {u,v,A,B,C,op,pthr,gid, rx,ry, pad,pad}
#define NBLK 1024
#define WC (64 * 64 * 9)

typedef short bhalf8 __attribute__((ext_vector_type(8)));
typedef float f32x4 __attribute__((ext_vector_type(4)));

__device__ __forceinline__ unsigned short f2bf(float f) {
    unsigned u = __float_as_uint(f);
    unsigned r = (u + 0x7fffu + ((u >> 16) & 1u)) >> 16;
    return (unsigned short)r;
}

// Coherent 8B load/store (agent scope -> sc0 sc1: bypass L1/L2, served at the
// coherent point). 2x fewer requests than scalar; HWC layout keeps them
// lane-contiguous for fabric coalescing.
__device__ __forceinline__ float2 cload8(const float* p) {
    unsigned long long u = __hip_atomic_load((const unsigned long long*)p,
        __ATOMIC_RELAXED, __HIP_MEMORY_SCOPE_AGENT);
    union { unsigned long long u; float2 f; } x; x.u = u;
    return x.f;
}
__device__ __forceinline__ void cstore8(float* p, float a, float b) {
    union { unsigned long long u; float f[2]; } x;
    x.f[0] = a; x.f[1] = b;
    __hip_atomic_store((unsigned long long*)p, x.u,
                       __ATOMIC_RELAXED, __HIP_MEMORY_SCOPE_AGENT);
}
__device__ __forceinline__ float cload(const float* p) {
    return __hip_atomic_load(p, __ATOMIC_RELAXED, __HIP_MEMORY_SCOPE_AGENT);
}

// ---------------------------------------------------------------------------
// Fence-free grid barrier (validated r6: ~us-scale). Coherent stores complete
// at the coherent point, so per-wave vmcnt(0) + tree counter suffices.
// ---------------------------------------------------------------------------
__device__ __forceinline__ void gbar(int* leaf, int* root, int* flag, int phase) {
    asm volatile("s_waitcnt vmcnt(0) lgkmcnt(0)" ::: "memory");
    __syncthreads();
    if (threadIdx.x == 0) {
        int g = blockIdx.x >> 5;
        int old = atomicAdd(&leaf[g * 16], 1);
        if ((old & 31) == 31) {
            int o2 = atomicAdd(root, 1);
            if ((o2 & 31) == 31)
                __hip_atomic_store(flag, phase, __ATOMIC_RELAXED,
                                   __HIP_MEMORY_SCOPE_AGENT);
        }
        while (__hip_atomic_load(flag, __ATOMIC_RELAXED,
                                 __HIP_MEMORY_SCOPE_AGENT) < phase)
            __builtin_amdgcn_s_sleep(4);
    }
    __syncthreads();
    asm volatile("" ::: "memory");
}

// ---------------------------------------------------------------------------
// Init launch: weight repack (0..197), splat precompute (198,199),
// zero barrier counters + stats accumulators (200).
// ---------------------------------------------------------------------------
__global__ void gls_init(const float* __restrict__ conv1_w,
                         const float* __restrict__ blk_w,
                         const float* __restrict__ up_w,
                         unsigned short* __restrict__ wprep,
                         const float* __restrict__ means,
                         const float* __restrict__ cov6,
                         const float* __restrict__ opac,
                         float* __restrict__ params,
                         int* __restrict__ counts,
                         int* __restrict__ barmem,
                         float* __restrict__ sacc)
{
    int bx = blockIdx.x;
    int tid = threadIdx.x;
    if (bx == 200) {
        for (int i = tid; i < 520; i += 256) barmem[i] = 0;
        if (tid < 128) sacc[tid] = 0.f;
        return;
    }
    if (bx < 198) {
        int p = bx % 18, c = bx / 18;
        const float* src;
        if (c == 0) src = conv1_w;
        else if (c <= 4) src = blk_w + (c - 1) * WC;
        else if (c == 5) src = conv1_w + WC;
        else if (c == 6) src = up_w;
        else src = blk_w + (c - 3) * WC;
        int tap = p >> 1;
        int m = tid >> 6, lane = tid & 63;
        int oc = m * 16 + (lane & 15);
        int ci0 = (p & 1) * 32 + (lane >> 4) * 8;
        unsigned short v[8];
#pragma unroll
        for (int j = 0; j < 8; ++j)
            v[j] = f2bf(src[(oc * 64 + ci0 + j) * 9 + tap]);
        unsigned short* dst = wprep + ((c * 18 + p) * 4 + m) * 64 * 8 + lane * 8;
#pragma unroll
        for (int j = 0; j < 8; ++j) dst[j] = v[j];
        return;
    }
    int s = bx - 198;
    __shared__ int s_base;
    __shared__ int s_wsum[4];
    if (tid == 0) s_base = 0;
    __syncthreads();
    float* P = params + s * G_N * PSTR;
    float H = (float)(100 << s);
    float sh = (float)(1 << s);
    for (int it = 0; it < G_N / 256; ++it) {
        int g = it * 256 + tid;
        float mx = means[g * 3 + 0], my = means[g * 3 + 1], mz = means[g * 3 + 2];
        float op = opac[g * 2 + s];
        bool mask = (mx >= -50.f && mx <= 50.f && my >= -50.f && my <= 50.f &&
                     mz >= -4.f && mz <= 4.f && op > 0.05f);
        unsigned long long bal = __ballot(mask);
        int lane = tid & 63, wid = tid >> 6;
        int prefix = __popcll(bal & ((1ull << lane) - 1ull));
        if (lane == 0) s_wsum[wid] = __popcll(bal);
        __syncthreads();
        int woff = 0;
        for (int w = 0; w < 4; ++w) if (w < wid) woff += s_wsum[w];
        int pos = s_base + woff + prefix;
        if (mask) {
            float u = -sh * my + 0.5f * H;
            float v = -sh * mx + 0.5f * H;
            float a = sh * sh * cov6[g * 6 + 3] + 0.3f;
            float c = sh * sh * cov6[g * 6 + 0] + 0.3f;
            float bb = sh * sh * cov6[g * 6 + 1];
            float det = fmaxf(a * c - bb * bb, 1e-8f);
            float t = logf(255.f * op);
            float* Q = P + pos * PSTR;
            Q[0] = u; Q[1] = v;
            Q[2] = c / det; Q[3] = -bb / det; Q[4] = a / det;
            Q[5] = op; Q[6] = -t;
            Q[7] = __int_as_float(g);
            Q[8] = sqrtf(2.f * t * a);
            Q[9] = sqrtf(2.f * t * c);
            Q[10] = 0.f; Q[11] = 0.f;
        }
        __syncthreads();
        if (tid == 0) s_base += s_wsum[0] + s_wsum[1] + s_wsum[2] + s_wsum[3];
        __syncthreads();
    }
    if (tid == 0) counts[s] = s_base;
}

// ---------------------------------------------------------------------------
// Render one 16x16 tile; output HWC via LDS-bounce + coalesced 8B cstores.
// ---------------------------------------------------------------------------
__device__ __forceinline__ void render_tile(
    int unit, const float* __restrict__ params, const int* __restrict__ counts,
    const float* __restrict__ feats, float* __restrict__ out0,
    float* __restrict__ out1, char* smem)
{
    int s = (unit < 49) ? 0 : 1;
    int t = (s == 0) ? unit : unit - 49;
    int tw = (s == 0) ? 7 : 13;
    int bxx = t % tw, byy = t / tw;
    int H = 100 << s;
    const float* P = params + s * G_N * PSTR;
    float* out = s ? out1 : out0;
    int cnt = counts[s];

    float* raw = (float*)smem;                 // 3072 f
    float* cmp = raw + CCH * PSTR;             // 3072 f
    int* s_wsum = (int*)(smem + 24576);

    int tid = threadIdx.x;
    int txl = tid & 15, tyl = tid >> 4;
    int px = bxx * 16 + txl;
    int py = byy * 16 + tyl;
    bool active = (px < H) && (py < H);
    float fx = (float)px, fy = (float)py;
    float tx0 = (float)(bxx * 16);
    float tx1 = (float)min(H - 1, bxx * 16 + 15);
    float ty0 = (float)(byy * 16);
    float ty1 = (float)min(H - 1, byy * 16 + 15);

    f32x4 acc[16];
#pragma unroll
    for (int k = 0; k < 16; ++k) acc[k] = (f32x4){0.f, 0.f, 0.f, 0.f};
    float T = 1.f;

    for (int base = 0; base < cnt; base += CCH) {
        int anyalive = __syncthreads_or((int)(active && T > 1e-6f));
        if (!anyalive) break;
        int n = min(CCH, cnt - base);
        for (int i = tid; i < n * 3; i += 256)
            ((float4*)raw)[i] = ((const float4*)(P + base * PSTR))[i];
        __syncthreads();
        bool pass = false;
        if (tid < n) {
            float u = raw[tid * PSTR + 0], v = raw[tid * PSTR + 1];
            float rx = raw[tid * PSTR + 8], ry = raw[tid * PSTR + 9];
            pass = (u + rx >= tx0) && (u - rx <= tx1) &&
                   (v + ry >= ty0) && (v - ry <= ty1);
        }
        unsigned long long bal = __ballot(pass);
        int lane = tid & 63, wid = tid >> 6;
        int prefix = __popcll(bal & ((1ull << lane) - 1ull));
        if (lane == 0) s_wsum[wid] = __popcll(bal);
        __syncthreads();
        int woff = 0;
        for (int w = 0; w < 4; ++w) if (w < wid) woff += s_wsum[w];
        if (pass) {
            float4* dst = (float4*)(cmp + (woff + prefix) * PSTR);
            const float4* src = (const float4*)(raw + tid * PSTR);
            dst[0] = src[0]; dst[1] = src[1]; dst[2] = src[2];
        }
        __syncthreads();
        int nc = s_wsum[0] + s_wsum[1] + s_wsum[2] + s_wsum[3];
        if (active && T > 1e-6f) {
            for (int j = 0; j < nc; ++j) {
                float4 q0 = *(const float4*)(cmp + j * PSTR);
                float4 q1 = *(const float4*)(cmp + j * PSTR + 4);
                float dx = q0.x - fx, dy = q0.y - fy;
                float power = -0.5f * (q0.z * dx * dx + q1.x * dy * dy) - q0.w * dx * dy;
                if (power <= 0.f && power >= q1.z) {
                    float alpha = fminf(q1.y * __expf(power), 0.99f);
                    float wgt = alpha * T;
                    const f32x4* f4 = (const f32x4*)(feats + __float_as_int(q1.w) * 64);
#pragma unroll
                    for (int k = 0; k < 16; ++k) {
                        f32x4 fv = f4[k];
                        acc[k][0] = fmaf(wgt, fv[0], acc[k][0]);
                        acc[k][1] = fmaf(wgt, fv[1], acc[k][1]);
                        acc[k][2] = fmaf(wgt, fv[2], acc[k][2]);
                        acc[k][3] = fmaf(wgt, fv[3], acc[k][3]);
                    }
                    T *= (1.f - alpha);
                }
            }
        }
    }

    // LDS-bounce epilogue: 4 row-groups of 4 rows, coalesced 8B coherent stores
    float* shf = (float*)smem;   // 64 px * 65 stride = 16640 B (raw/cmp dead)
    for (int g = 0; g < 4; ++g) {
        __syncthreads();
        if ((tyl >> 2) == g) {
            int lp = (tyl & 3) * 16 + txl;
#pragma unroll
            for (int k = 0; k < 16; ++k) {
                shf[lp * 65 + 4 * k + 0] = acc[k][0];
                shf[lp * 65 + 4 * k + 1] = acc[k][1];
                shf[lp * 65 + 4 * k + 2] = acc[k][2];
                shf[lp * 65 + 4 * k + 3] = acc[k][3];
            }
        }
        __syncthreads();
        for (int j = tid; j < 2048; j += 256) {
            int row = j >> 9, w = j & 511;
            int pl = w >> 5, cp = (w & 31) * 2;
            int gy = byy * 16 + g * 4 + row;
            int gx = bxx * 16 + pl;
            if (gy < H && gx < H)
                cstore8(&out[((gy * H + gx) << 6) + cp],
                        shf[(row * 16 + pl) * 65 + cp],
                        shf[(row * 16 + pl) * 65 + cp + 1]);
        }
    }
}

// ---------------------------------------------------------------------------
// MFMA conv3x3 tile (8x8 px x 64 oc), activations HWC, 8B coherent traffic.
// ups: stage 8x8x64 f32 source tile in LDS, bilinear from LDS.
// nrm: instance-norm + skip-add staging; writes nout.
// nchw: final conv — relu(conv+add) with normal NCHW stores to d_out.
// mode: 0 none, 1 relu, 2 relu(conv+add), 4 conv + bev_emb (cached float2)
// ---------------------------------------------------------------------------
__device__ __forceinline__ void conv_tile(
    int bx, int H,
    const float* __restrict__ in, const unsigned short* __restrict__ wp,
    const float* __restrict__ add, float* __restrict__ out,
    int mode, int ups, int nrm, int dostats, int nchw,
    const float* __restrict__ nskip, const float* __restrict__ sraw,
    float* __restrict__ nout, float* __restrict__ sacc,
    char* smem)
{
    float* fin = (float*)smem;                            // 16384 B (ups only)
    unsigned short* xlds = (unsigned short*)(smem + 16384); // 14400 B
    float* nm  = (float*)(smem + 30784);                  // 64
    float* nr  = nm + 64;                                 // 64
    float* red = nr + 64;                                 // 512

    int tid = threadIdx.x;
    int gw = (H + 7) >> 3;
    int by = bx / gw, bxx = bx - by * gw;
    int y0 = by * 8, x0 = bxx * 8;
    int w = tid >> 6, lane = tid & 63;
    int n = lane & 15, q = lane >> 4;
    int Hh = H >> 1;
    int oy = (y0 >> 1) - 2, ox = (x0 >> 1) - 2;

    if (nrm) {
        if (tid < 64) {
            float s = cload(&sraw[tid]), s2 = cload(&sraw[64 + tid]);
            float mean = s * (1.f / 40000.f);
            float var = s2 * (1.f / 40000.f) - mean * mean;
            nm[tid] = mean;
            nr[tid] = rsqrtf(var + 1e-5f);
        }
        __syncthreads();
    }
    if (ups) {
        // stage 8x8x64 f32 source tile
        for (int i = tid; i < 2048; i += 256) {
            int pxi = i >> 5, cp = (i & 31) * 2;
            int iy = pxi >> 3, ix = pxi & 7;
            int gyi = oy + iy, gxi = ox + ix;
            float2 v = {0.f, 0.f};
            if (gyi >= 0 && gyi < Hh && gxi >= 0 && gxi < Hh)
                v = cload8(&in[((gyi * Hh + gxi) << 6) + cp]);
            *(float2*)&fin[((iy * 8 + ix) << 6) + cp] = v;
        }
        __syncthreads();
    }

    // ---- stage 10x10 halo x 64ch as bf16 HWC into xlds ----
    for (int i = tid; i < 3200; i += 256) {
        int px = i >> 5, cp = (i & 31) * 2;
        int yy = px / 10, xx = px - yy * 10;
        int gy = y0 - 1 + yy, gx = x0 - 1 + xx;
        float2 v = {0.f, 0.f};
        bool ib = (gy >= 0 && gy < H && gx >= 0 && gx < H);
        if (ib) {
            if (ups) {
                int yi = gy >> 1, xi = gx >> 1;
                int yb = (gy & 1) ? min(yi + 1, Hh - 1) : max(yi - 1, 0);
                int xb = (gx & 1) ? min(xi + 1, Hh - 1) : max(xi - 1, 0);
                int t0 = yi - oy, t1 = xi - ox, t2 = yb - oy, t3 = xb - ox;
                float2 f00 = *(const float2*)&fin[((t0 * 8 + t1) << 6) + cp];
                float2 f01 = *(const float2*)&fin[((t0 * 8 + t3) << 6) + cp];
                float2 f10 = *(const float2*)&fin[((t2 * 8 + t1) << 6) + cp];
                float2 f11 = *(const float2*)&fin[((t2 * 8 + t3) << 6) + cp];
                v.x = 0.5625f * f00.x + 0.1875f * (f01.x + f10.x) + 0.0625f * f11.x;
                v.y = 0.5625f * f00.y + 0.1875f * (f01.y + f10.y) + 0.0625f * f11.y;
            } else if (nrm) {
                int off = ((gy * H + gx) << 6) + cp;
                float2 a = cload8(&in[off]);
                float2 b = cload8(&nskip[off]);
                v.x = (a.x - nm[cp]) * nr[cp] + b.x;
                v.y = (a.y - nm[cp + 1]) * nr[cp + 1] + b.y;
                cstore8(&nout[off], v.x, v.y);   // halo dups: identical values
            } else {
                v = cload8(&in[((gy * H + gx) << 6) + cp]);
            }
        }
        ushort2 u2 = { f2bf(v.x), f2bf(v.y) };
        *(ushort2*)&xlds[px * 72 + cp] = u2;
    }
    __syncthreads();

    f32x4 acc[4];
#pragma unroll
    for (int m = 0; m < 4; ++m) acc[m] = (f32x4){0.f, 0.f, 0.f, 0.f};
    const bhalf8* wp8 = (const bhalf8*)wp;
    int sy = 2 * w + (n >> 3), sx = n & 7;

    bhalf8 a0 = wp8[0 * 64 + lane];
    bhalf8 a1 = wp8[1 * 64 + lane];
    bhalf8 a2 = wp8[2 * 64 + lane];
    bhalf8 a3 = wp8[3 * 64 + lane];
    bhalf8 bb = *(const bhalf8*)&xlds[(sy * 10 + sx) * 72 + q * 8];

#pragma unroll 1
    for (int p = 0; p < 18; ++p) {
        bhalf8 na0, na1, na2, na3, nbb;
        if (p < 17) {
            int pn = p + 1;
            na0 = wp8[(pn * 4 + 0) * 64 + lane];
            na1 = wp8[(pn * 4 + 1) * 64 + lane];
            na2 = wp8[(pn * 4 + 2) * 64 + lane];
            na3 = wp8[(pn * 4 + 3) * 64 + lane];
            int tap = pn >> 1, ch = pn & 1;
            int dy = tap / 3, dx = tap - dy * 3;
            nbb = *(const bhalf8*)&xlds[((sy + dy) * 10 + sx + dx) * 72 + ch * 32 + q * 8];
        }
        acc[0] = __builtin_amdgcn_mfma_f32_16x16x32_bf16(a0, bb, acc[0], 0, 0, 0);
        acc[1] = __builtin_amdgcn_mfma_f32_16x16x32_bf16(a1, bb, acc[1], 0, 0, 0);
        acc[2] = __builtin_amdgcn_mfma_f32_16x16x32_bf16(a2, bb, acc[2], 0, 0, 0);
        acc[3] = __builtin_amdgcn_mfma_f32_16x16x32_bf16(a3, bb, acc[3], 0, 0, 0);
        a0 = na0; a1 = na1; a2 = na2; a3 = na3; bb = nbb;
    }

    int gy = y0 + sy, gx = x0 + sx;
    if (gy < H && gx < H) {
        int base = (gy * H + gx) << 6;
        if (nchw) {
            // final conv: relu(conv + add), normal NCHW stores to d_out
#pragma unroll
            for (int m = 0; m < 4; ++m)
#pragma unroll
                for (int rp = 0; rp < 2; ++rp) {
                    int oc = m * 16 + q * 4 + rp * 2;
                    float2 av = cload8(&add[base + oc]);
                    out[oc * H * H + gy * H + gx] = fmaxf(acc[m][rp * 2] + av.x, 0.f);
                    out[(oc + 1) * H * H + gy * H + gx] = fmaxf(acc[m][rp * 2 + 1] + av.y, 0.f);
                }
        } else {
#pragma unroll
            for (int m = 0; m < 4; ++m)
#pragma unroll
                for (int rp = 0; rp < 2; ++rp) {
                    int oc = m * 16 + q * 4 + rp * 2;
                    float v0 = acc[m][rp * 2], v1 = acc[m][rp * 2 + 1];
                    if (mode == 1) { v0 = fmaxf(v0, 0.f); v1 = fmaxf(v1, 0.f); }
                    else if (mode == 2) {
                        float2 av = cload8(&add[base + oc]);
                        v0 = fmaxf(v0 + av.x, 0.f); v1 = fmaxf(v1 + av.y, 0.f);
                    } else if (mode == 4) {
                        float2 av = *(const float2*)&add[base + oc];  // bev_emb: input, cached
                        v0 += av.x; v1 += av.y;
                    }
                    cstore8(&out[base + oc], v0, v1);
                }
        }
    }

    if (dostats) {
#pragma unroll
        for (int m = 0; m < 4; ++m)
#pragma unroll
            for (int r = 0; r < 4; ++r) {
                float v = acc[m][r];
                float s = v, s2 = v * v;
#pragma unroll
                for (int d = 1; d < 16; d <<= 1) {
                    s += __shfl_xor(s, d, 64);
                    s2 += __shfl_xor(s2, d, 64);
                }
                if (n == 0) {
                    int oc = m * 16 + q * 4 + r;
                    red[w * 128 + oc] = s;
                    red[w * 128 + 64 + oc] = s2;
                }
            }
        __syncthreads();
        if (tid < 128) {
            float t = red[tid] + red[128 + tid] + red[256 + tid] + red[384 + tid];
            atomicAdd(&sacc[tid], t);
        }
    }
}

// ---------------------------------------------------------------------------
// Persistent megakernel: 11 phases, 10 grid barriers.
// ---------------------------------------------------------------------------
__global__ __launch_bounds__(256, 4) void gls_mega(
    const float* __restrict__ feats, const float* __restrict__ bev_emb,
    const unsigned short* __restrict__ wprep,
    const float* __restrict__ params, const int* __restrict__ cnts,
    float* __restrict__ R0, float* __restrict__ A0,
    float* __restrict__ T0, float* __restrict__ B0,
    float* __restrict__ Q0, float* __restrict__ Q1,
    float* __restrict__ Q2, float* __restrict__ Q3,
    float* __restrict__ out, int* __restrict__ barmem, float* __restrict__ sacc)
{
    __shared__ __align__(16) char smem[33408];
    int bid = blockIdx.x;
    int* leaf = barmem;
    int* root = barmem + 512;
    int* flag = barmem + 513;
    int ph = 0;

    // P1: render both stages (218 tiles), HWC outputs
    if (bid < 218) render_tile(bid, params, cnts, feats, R0, Q0, smem);
    gbar(leaf, root, flag, ++ph);

    // P2: c0 (H100, +bev_emb) || c5 (H200 skip conv)
    if (bid < 169)
        conv_tile(bid, 100, R0, wprep + 0 * WC, bev_emb, A0, 4, 0, 0, 0, 0,
                  nullptr, nullptr, nullptr, nullptr, smem);
    else if (bid < 794)
        conv_tile(bid - 169, 200, Q0, wprep + 5 * WC, nullptr, Q1, 0, 0, 0, 0, 0,
                  nullptr, nullptr, nullptr, nullptr, smem);
    gbar(leaf, root, flag, ++ph);

    // P3..P6: H100 basic blocks
    if (bid < 169)
        conv_tile(bid, 100, A0, wprep + 1 * WC, nullptr, T0, 1, 0, 0, 0, 0,
                  nullptr, nullptr, nullptr, nullptr, smem);
    gbar(leaf, root, flag, ++ph);
    if (bid < 169)
        conv_tile(bid, 100, T0, wprep + 2 * WC, A0, B0, 2, 0, 0, 0, 0,
                  nullptr, nullptr, nullptr, nullptr, smem);
    gbar(leaf, root, flag, ++ph);
    if (bid < 169)
        conv_tile(bid, 100, B0, wprep + 3 * WC, nullptr, T0, 1, 0, 0, 0, 0,
                  nullptr, nullptr, nullptr, nullptr, smem);
    gbar(leaf, root, flag, ++ph);
    if (bid < 169)
        conv_tile(bid, 100, T0, wprep + 4 * WC, B0, A0, 2, 0, 0, 0, 0,
                  nullptr, nullptr, nullptr, nullptr, smem);
    gbar(leaf, root, flag, ++ph);

    // P7: upconv (LDS-tile bilinear) + instance-norm stats
    if (bid < 625)
        conv_tile(bid, 200, A0, wprep + 6 * WC, nullptr, Q3, 0, 1, 0, 1, 0,
                  nullptr, nullptr, nullptr, sacc, smem);
    gbar(leaf, root, flag, ++ph);

    // P8: c7 with fused instance-norm + skip-add staging (materializes Q0)
    if (bid < 625)
        conv_tile(bid, 200, Q3, wprep + 7 * WC, nullptr, Q2, 1, 0, 1, 0, 0,
                  Q1, sacc, Q0, nullptr, smem);
    gbar(leaf, root, flag, ++ph);

    // P9..P11: H200 basic blocks; final conv writes d_out (NCHW, cached)
    if (bid < 625)
        conv_tile(bid, 200, Q2, wprep + 8 * WC, Q0, Q1, 2, 0, 0, 0, 0,
                  nullptr, nullptr, nullptr, nullptr, smem);
    gbar(leaf, root, flag, ++ph);
    if (bid < 625)
        conv_tile(bid, 200, Q1, wprep + 9 * WC, nullptr, Q2, 1, 0, 0, 0, 0,
                  nullptr, nullptr, nullptr, nullptr, smem);
    gbar(leaf, root, flag, ++ph);
    if (bid == 0 && threadIdx.x == 0)
        out[2560000] = (float)(cnts[0] + cnts[1]);
    if (bid < 625)
        conv_tile(bid, 200, Q2, wprep + 10 * WC, Q1, out, 2, 0, 0, 0, 1,
                  nullptr, nullptr, nullptr, nullptr, smem);
}

// ---------------------------------------------------------------------------
extern "C" void kernel_launch(void* const* d_in, const int* in_sizes, int n_in,
                              void* d_out, int out_size, void* d_ws, size_t ws_size,
                              hipStream_t stream)
{
    const float* feats   = (const float*)d_in[0];
    const float* means   = (const float*)d_in[1];
    const float* cov6    = (const float*)d_in[2];
    const float* opac    = (const float*)d_in[3];
    const float* bev_emb = (const float*)d_in[4];
    const float* conv1_w = (const float*)d_in[5];
    const float* blk_w   = (const float*)d_in[6];
    const float* up_w    = (const float*)d_in[7];
    float* out = (float*)d_out;
    float* ws = (float*)d_ws;

    float* P      = ws;                          // 49152 floats
    int*   cnts   = (int*)(ws + 49152);
    int*   barmem = (int*)(ws + 49280);          // 520 ints
    float* sacc   = ws + 49856;                  // 128 floats
    unsigned short* wprep = (unsigned short*)(ws + 50176);  // 11*36864 u16
    float* R0 = ws + 262144;                     // 640000 (H=100, HWC)
    float* A0 = ws + 917504;
    float* T0 = ws + 1572864;
    float* B0 = ws + 2228224;
    float* Q0 = ws + 2883584;                    // 2560000 (H=200, HWC)
    float* Q1 = ws + 5505024;
    float* Q2 = ws + 8126464;
    float* Q3 = ws + 10747904;

    gls_init<<<201, 256, 0, stream>>>(conv1_w, blk_w, up_w, wprep,
                                      means, cov6, opac, P, cnts, barmem, sacc);
    gls_mega<<<NBLK, 256, 0, stream>>>(feats, bev_emb, wprep, P, cnts,
                                       R0, A0, T0, B0, Q0, Q1, Q2, Q3,
                                       out, barmem, sacc);
    (void)in_sizes; (void)n_in; (void)out_size; (void)ws_size;
}

// Round 8
// 281.686 us; speedup vs baseline: 8.5034x; 1.2799x over previous
//
#include <hip/hip_runtime.h>
#include <math.h>

#define G_N 2048
#define CCH 256
#define PSTR 12   // {u,v,A,B,C,op,pthr,gid, rx,ry, pad,pad}
#define NBLK 1024
#define WC (64 * 64 * 9)

typedef short bhalf8 __attribute__((ext_vector_type(8)));
typedef float f32x4 __attribute__((ext_vector_type(4)));
typedef unsigned short u16;

__device__ __forceinline__ u16 f2bf(float f) {
    unsigned u = __float_as_uint(f);
    unsigned r = (u + 0x7fffu + ((u >> 16) & 1u)) >> 16;
    return (u16)r;
}
__device__ __forceinline__ float b2f(u16 h) {
    return __uint_as_float((unsigned)h << 16);
}

// Coherent 8B (4 x bf16) load/store: agent scope -> sc0 sc1, bypass L1/L2,
// served at the coherent point. HWC layout keeps them lane-contiguous.
__device__ __forceinline__ ushort4 chload4(const u16* p) {
    unsigned long long u = __hip_atomic_load((const unsigned long long*)p,
        __ATOMIC_RELAXED, __HIP_MEMORY_SCOPE_AGENT);
    union { unsigned long long u; ushort4 s; } x; x.u = u;
    return x.s;
}
__device__ __forceinline__ void chstore4(u16* p, ushort4 v) {
    union { unsigned long long u; ushort4 s; } x; x.s = v;
    __hip_atomic_store((unsigned long long*)p, x.u,
                       __ATOMIC_RELAXED, __HIP_MEMORY_SCOPE_AGENT);
}
__device__ __forceinline__ float cload(const float* p) {
    return __hip_atomic_load(p, __ATOMIC_RELAXED, __HIP_MEMORY_SCOPE_AGENT);
}

// Fence-free grid barrier (validated r6/r7).
__device__ __forceinline__ void gbar(int* leaf, int* root, int* flag, int phase) {
    asm volatile("s_waitcnt vmcnt(0) lgkmcnt(0)" ::: "memory");
    __syncthreads();
    if (threadIdx.x == 0) {
        int g = blockIdx.x >> 5;
        int old = atomicAdd(&leaf[g * 16], 1);
        if ((old & 31) == 31) {
            int o2 = atomicAdd(root, 1);
            if ((o2 & 31) == 31)
                __hip_atomic_store(flag, phase, __ATOMIC_RELAXED,
                                   __HIP_MEMORY_SCOPE_AGENT);
        }
        while (__hip_atomic_load(flag, __ATOMIC_RELAXED,
                                 __HIP_MEMORY_SCOPE_AGENT) < phase)
            __builtin_amdgcn_s_sleep(4);
    }
    __syncthreads();
    asm volatile("" ::: "memory");
}

// ---------------------------------------------------------------------------
// Init: weight repack (0..197), splat precompute (198,199), zero counters (200)
// ---------------------------------------------------------------------------
__global__ void gls_init(const float* __restrict__ conv1_w,
                         const float* __restrict__ blk_w,
                         const float* __restrict__ up_w,
                         u16* __restrict__ wprep,
                         const float* __restrict__ means,
                         const float* __restrict__ cov6,
                         const float* __restrict__ opac,
                         float* __restrict__ params,
                         int* __restrict__ counts,
                         int* __restrict__ barmem,
                         float* __restrict__ sacc)
{
    int bx = blockIdx.x;
    int tid = threadIdx.x;
    if (bx == 200) {
        for (int i = tid; i < 520; i += 256) barmem[i] = 0;
        if (tid < 128) sacc[tid] = 0.f;
        return;
    }
    if (bx < 198) {
        int p = bx % 18, c = bx / 18;
        const float* src;
        if (c == 0) src = conv1_w;
        else if (c <= 4) src = blk_w + (c - 1) * WC;
        else if (c == 5) src = conv1_w + WC;
        else if (c == 6) src = up_w;
        else src = blk_w + (c - 3) * WC;
        int tap = p >> 1;
        int m = tid >> 6, lane = tid & 63;
        int oc = m * 16 + (lane & 15);
        int ci0 = (p & 1) * 32 + (lane >> 4) * 8;
        u16 v[8];
#pragma unroll
        for (int j = 0; j < 8; ++j)
            v[j] = f2bf(src[(oc * 64 + ci0 + j) * 9 + tap]);
        u16* dst = wprep + ((c * 18 + p) * 4 + m) * 64 * 8 + lane * 8;
#pragma unroll
        for (int j = 0; j < 8; ++j) dst[j] = v[j];
        return;
    }
    int s = bx - 198;
    __shared__ int s_base;
    __shared__ int s_wsum[4];
    if (tid == 0) s_base = 0;
    __syncthreads();
    float* P = params + s * G_N * PSTR;
    float H = (float)(100 << s);
    float sh = (float)(1 << s);
    for (int it = 0; it < G_N / 256; ++it) {
        int g = it * 256 + tid;
        float mx = means[g * 3 + 0], my = means[g * 3 + 1], mz = means[g * 3 + 2];
        float op = opac[g * 2 + s];
        bool mask = (mx >= -50.f && mx <= 50.f && my >= -50.f && my <= 50.f &&
                     mz >= -4.f && mz <= 4.f && op > 0.05f);
        unsigned long long bal = __ballot(mask);
        int lane = tid & 63, wid = tid >> 6;
        int prefix = __popcll(bal & ((1ull << lane) - 1ull));
        if (lane == 0) s_wsum[wid] = __popcll(bal);
        __syncthreads();
        int woff = 0;
        for (int w = 0; w < 4; ++w) if (w < wid) woff += s_wsum[w];
        int pos = s_base + woff + prefix;
        if (mask) {
            float u = -sh * my + 0.5f * H;
            float v = -sh * mx + 0.5f * H;
            float a = sh * sh * cov6[g * 6 + 3] + 0.3f;
            float c = sh * sh * cov6[g * 6 + 0] + 0.3f;
            float bb = sh * sh * cov6[g * 6 + 1];
            float det = fmaxf(a * c - bb * bb, 1e-8f);
            float t = logf(255.f * op);
            float* Q = P + pos * PSTR;
            Q[0] = u; Q[1] = v;
            Q[2] = c / det; Q[3] = -bb / det; Q[4] = a / det;
            Q[5] = op; Q[6] = -t;
            Q[7] = __int_as_float(g);
            Q[8] = sqrtf(2.f * t * a);
            Q[9] = sqrtf(2.f * t * c);
            Q[10] = 0.f; Q[11] = 0.f;
        }
        __syncthreads();
        if (tid == 0) s_base += s_wsum[0] + s_wsum[1] + s_wsum[2] + s_wsum[3];
        __syncthreads();
    }
    if (tid == 0) counts[s] = s_base;
}

// ---------------------------------------------------------------------------
// Render one 16x16 tile; bf16 HWC output via LDS-bounce coalesced 8B cstores.
// ---------------------------------------------------------------------------
__device__ __forceinline__ void render_tile(
    int unit, const float* __restrict__ params, const int* __restrict__ counts,
    const float* __restrict__ feats, u16* __restrict__ out0,
    u16* __restrict__ out1, char* smem)
{
    int s = (unit < 49) ? 0 : 1;
    int t = (s == 0) ? unit : unit - 49;
    int tw = (s == 0) ? 7 : 13;
    int bxx = t % tw, byy = t / tw;
    int H = 100 << s;
    const float* P = params + s * G_N * PSTR;
    u16* out = s ? out1 : out0;
    int cnt = counts[s];

    float* raw = (float*)smem;
    float* cmp = raw + CCH * PSTR;
    int* s_wsum = (int*)(smem + 24576);

    int tid = threadIdx.x;
    int txl = tid & 15, tyl = tid >> 4;
    int px = bxx * 16 + txl;
    int py = byy * 16 + tyl;
    bool active = (px < H) && (py < H);
    float fx = (float)px, fy = (float)py;
    float tx0 = (float)(bxx * 16);
    float tx1 = (float)min(H - 1, bxx * 16 + 15);
    float ty0 = (float)(byy * 16);
    float ty1 = (float)min(H - 1, byy * 16 + 15);

    f32x4 acc[16];
#pragma unroll
    for (int k = 0; k < 16; ++k) acc[k] = (f32x4){0.f, 0.f, 0.f, 0.f};
    float T = 1.f;

    for (int base = 0; base < cnt; base += CCH) {
        int anyalive = __syncthreads_or((int)(active && T > 1e-6f));
        if (!anyalive) break;
        int n = min(CCH, cnt - base);
        for (int i = tid; i < n * 3; i += 256)
            ((float4*)raw)[i] = ((const float4*)(P + base * PSTR))[i];
        __syncthreads();
        bool pass = false;
        if (tid < n) {
            float u = raw[tid * PSTR + 0], v = raw[tid * PSTR + 1];
            float rx = raw[tid * PSTR + 8], ry = raw[tid * PSTR + 9];
            pass = (u + rx >= tx0) && (u - rx <= tx1) &&
                   (v + ry >= ty0) && (v - ry <= ty1);
        }
        unsigned long long bal = __ballot(pass);
        int lane = tid & 63, wid = tid >> 6;
        int prefix = __popcll(bal & ((1ull << lane) - 1ull));
        if (lane == 0) s_wsum[wid] = __popcll(bal);
        __syncthreads();
        int woff = 0;
        for (int w = 0; w < 4; ++w) if (w < wid) woff += s_wsum[w];
        if (pass) {
            float4* dst = (float4*)(cmp + (woff + prefix) * PSTR);
            const float4* src = (const float4*)(raw + tid * PSTR);
            dst[0] = src[0]; dst[1] = src[1]; dst[2] = src[2];
        }
        __syncthreads();
        int nc = s_wsum[0] + s_wsum[1] + s_wsum[2] + s_wsum[3];
        if (active && T > 1e-6f) {
            for (int j = 0; j < nc; ++j) {
                float4 q0 = *(const float4*)(cmp + j * PSTR);
                float4 q1 = *(const float4*)(cmp + j * PSTR + 4);
                float dx = q0.x - fx, dy = q0.y - fy;
                float power = -0.5f * (q0.z * dx * dx + q1.x * dy * dy) - q0.w * dx * dy;
                if (power <= 0.f && power >= q1.z) {
                    float alpha = fminf(q1.y * __expf(power), 0.99f);
                    float wgt = alpha * T;
                    const f32x4* f4 = (const f32x4*)(feats + __float_as_int(q1.w) * 64);
#pragma unroll
                    for (int k = 0; k < 16; ++k) {
                        f32x4 fv = f4[k];
                        acc[k][0] = fmaf(wgt, fv[0], acc[k][0]);
                        acc[k][1] = fmaf(wgt, fv[1], acc[k][1]);
                        acc[k][2] = fmaf(wgt, fv[2], acc[k][2]);
                        acc[k][3] = fmaf(wgt, fv[3], acc[k][3]);
                    }
                    T *= (1.f - alpha);
                }
            }
        }
    }

    float* shf = (float*)smem;   // 64 px * 68 stride f32 (raw/cmp dead)
    for (int g = 0; g < 4; ++g) {
        __syncthreads();
        if ((tyl >> 2) == g) {
            int lp = (tyl & 3) * 16 + txl;
#pragma unroll
            for (int k = 0; k < 16; ++k)
                *(float4*)&shf[lp * 68 + 4 * k] =
                    (float4){acc[k][0], acc[k][1], acc[k][2], acc[k][3]};
        }
        __syncthreads();
        for (int j = tid; j < 1024; j += 256) {
            int lp = j >> 4, c4 = (j & 15) * 4;
            int gy = byy * 16 + g * 4 + (lp >> 4);
            int gx = bxx * 16 + (lp & 15);
            if (gy < H && gx < H) {
                float4 v = *(float4*)&shf[lp * 68 + c4];
                ushort4 o = { f2bf(v.x), f2bf(v.y), f2bf(v.z), f2bf(v.w) };
                chstore4(&out[((gy * H + gx) << 6) + c4], o);
            }
        }
    }
}

// ---------------------------------------------------------------------------
// Single MFMA conv3x3 tile (8x8 px x 64 oc). bf16 HWC coherent IO.
// bev != nullptr: epilogue += bev_emb (f32 cached, HWC-indexed).
// ups: input is H/2 bf16 HWC; bilinear via LDS source tile.
// dostats: accumulate per-channel sum/sumsq into sacc.
// ---------------------------------------------------------------------------
__device__ __forceinline__ void conv_tile(
    int bx, int H, const u16* __restrict__ in, const u16* __restrict__ wp,
    const float* __restrict__ bev, u16* __restrict__ outb,
    int ups, int dostats, float* __restrict__ sacc, char* smem)
{
    u16* xlds = (u16*)smem;                  // 100*72*2 = 14400 B
    u16* fin  = (u16*)(smem + 14400);        // 64*68*2 = 8704 B (ups only)
    float* red = (float*)(smem + 16384 + 8704);  // 512 f (after fin dead)

    int tid = threadIdx.x;
    int gw = (H + 7) >> 3;
    int by = bx / gw, bxx = bx - by * gw;
    int y0 = by * 8, x0 = bxx * 8;
    int w = tid >> 6, lane = tid & 63;
    int n = lane & 15, q = lane >> 4;
    int Hh = H >> 1;
    int oy = (y0 >> 1) - 2, ox = (x0 >> 1) - 2;

    if (ups) {
        for (int i = tid; i < 1024; i += 256) {
            int px = i >> 4, c4 = (i & 15) * 4;
            int iy = px >> 3, ix = px & 7;
            int gyi = oy + iy, gxi = ox + ix;
            ushort4 v = {0, 0, 0, 0};
            if (gyi >= 0 && gyi < Hh && gxi >= 0 && gxi < Hh)
                v = chload4(&in[((gyi * Hh + gxi) << 6) + c4]);
            *(ushort4*)&fin[px * 68 + c4] = v;
        }
        __syncthreads();
    }

    for (int i = tid; i < 1600; i += 256) {
        int px = i >> 4, c4 = (i & 15) * 4;
        int yy = px / 10, xx = px - yy * 10;
        int gy = y0 - 1 + yy, gx = x0 - 1 + xx;
        ushort4 v = {0, 0, 0, 0};
        if (gy >= 0 && gy < H && gx >= 0 && gx < H) {
            if (ups) {
                int yi = gy >> 1, xi = gx >> 1;
                int yb = (gy & 1) ? min(yi + 1, Hh - 1) : max(yi - 1, 0);
                int xb = (gx & 1) ? min(xi + 1, Hh - 1) : max(xi - 1, 0);
                int t0 = yi - oy, t1 = xi - ox, t2 = yb - oy, t3 = xb - ox;
                ushort4 f00 = *(const ushort4*)&fin[(t0 * 8 + t1) * 68 + c4];
                ushort4 f01 = *(const ushort4*)&fin[(t0 * 8 + t3) * 68 + c4];
                ushort4 f10 = *(const ushort4*)&fin[(t2 * 8 + t1) * 68 + c4];
                ushort4 f11 = *(const ushort4*)&fin[(t2 * 8 + t3) * 68 + c4];
                v.x = f2bf(0.5625f * b2f(f00.x) + 0.1875f * (b2f(f01.x) + b2f(f10.x)) + 0.0625f * b2f(f11.x));
                v.y = f2bf(0.5625f * b2f(f00.y) + 0.1875f * (b2f(f01.y) + b2f(f10.y)) + 0.0625f * b2f(f11.y));
                v.z = f2bf(0.5625f * b2f(f00.z) + 0.1875f * (b2f(f01.z) + b2f(f10.z)) + 0.0625f * b2f(f11.z));
                v.w = f2bf(0.5625f * b2f(f00.w) + 0.1875f * (b2f(f01.w) + b2f(f10.w)) + 0.0625f * b2f(f11.w));
            } else {
                v = chload4(&in[((gy * H + gx) << 6) + c4]);
            }
        }
        *(ushort4*)&xlds[px * 72 + c4] = v;
    }
    __syncthreads();

    f32x4 acc[4];
#pragma unroll
    for (int m = 0; m < 4; ++m) acc[m] = (f32x4){0.f, 0.f, 0.f, 0.f};
    const bhalf8* wp8 = (const bhalf8*)wp;
    int sy = 2 * w + (n >> 3), sx = n & 7;

    bhalf8 a0 = wp8[0 * 64 + lane];
    bhalf8 a1 = wp8[1 * 64 + lane];
    bhalf8 a2 = wp8[2 * 64 + lane];
    bhalf8 a3 = wp8[3 * 64 + lane];
    bhalf8 bb = *(const bhalf8*)&xlds[(sy * 10 + sx) * 72 + q * 8];

#pragma unroll 1
    for (int p = 0; p < 18; ++p) {
        bhalf8 na0, na1, na2, na3, nbb;
        if (p < 17) {
            int pn = p + 1;
            na0 = wp8[(pn * 4 + 0) * 64 + lane];
            na1 = wp8[(pn * 4 + 1) * 64 + lane];
            na2 = wp8[(pn * 4 + 2) * 64 + lane];
            na3 = wp8[(pn * 4 + 3) * 64 + lane];
            int tap = pn >> 1, ch = pn & 1;
            int dy = tap / 3, dx = tap - dy * 3;
            nbb = *(const bhalf8*)&xlds[((sy + dy) * 10 + sx + dx) * 72 + ch * 32 + q * 8];
        }
        acc[0] = __builtin_amdgcn_mfma_f32_16x16x32_bf16(a0, bb, acc[0], 0, 0, 0);
        acc[1] = __builtin_amdgcn_mfma_f32_16x16x32_bf16(a1, bb, acc[1], 0, 0, 0);
        acc[2] = __builtin_amdgcn_mfma_f32_16x16x32_bf16(a2, bb, acc[2], 0, 0, 0);
        acc[3] = __builtin_amdgcn_mfma_f32_16x16x32_bf16(a3, bb, acc[3], 0, 0, 0);
        a0 = na0; a1 = na1; a2 = na2; a3 = na3; bb = nbb;
    }

    int gy = y0 + sy, gx = x0 + sx;
    if (gy < H && gx < H) {
        int base = (gy * H + gx) << 6;
#pragma unroll
        for (int m = 0; m < 4; ++m) {
            int oc0 = m * 16 + q * 4;
            float v0 = acc[m][0], v1 = acc[m][1], v2 = acc[m][2], v3 = acc[m][3];
            if (bev) {
                float4 av = *(const float4*)&bev[base + oc0];
                v0 += av.x; v1 += av.y; v2 += av.z; v3 += av.w;
            }
            ushort4 o = { f2bf(v0), f2bf(v1), f2bf(v2), f2bf(v3) };
            chstore4(&outb[base + oc0], o);
        }
    }

    if (dostats) {
#pragma unroll
        for (int m = 0; m < 4; ++m)
#pragma unroll
            for (int r = 0; r < 4; ++r) {
                float v = acc[m][r];
                float s = v, s2 = v * v;
#pragma unroll
                for (int d = 1; d < 16; d <<= 1) {
                    s += __shfl_xor(s, d, 64);
                    s2 += __shfl_xor(s2, d, 64);
                }
                if (n == 0) {
                    int oc = m * 16 + q * 4 + r;
                    red[w * 128 + oc] = s;
                    red[w * 128 + 64 + oc] = s2;
                }
            }
        __syncthreads();
        if (tid < 128) {
            float t = red[tid] + red[128 + tid] + red[256 + tid] + red[384 + tid];
            atomicAdd(&sacc[tid], t);
        }
    }
}

// ---------------------------------------------------------------------------
// FUSED basic block: out = relu(x + conv2(relu(conv1(x)))).
// conv1 -> 10x10 intermediate in LDS (zeroed outside image = SAME pad),
// conv2 8x8 from LDS, residual from staged input tile. One phase, no
// intermediate HBM round-trip.
// nrm: staging computes x = instnorm(in)+nskip (norm stats from sraw).
// final_: epilogue writes f32 NCHW to outf (d_out); else bf16 HWC to outb.
// ---------------------------------------------------------------------------
__device__ __forceinline__ void bb_tile(
    int bx, int H, const u16* __restrict__ in,
    const u16* __restrict__ wp1, const u16* __restrict__ wp2,
    u16* __restrict__ outb, float* __restrict__ outf, int final_,
    int nrm, const u16* __restrict__ nskip, const float* __restrict__ sraw,
    char* smem)
{
    u16* xin  = (u16*)smem;              // 144 px * 72 = 20736 B
    u16* ilds = (u16*)(smem + 20736);    // 100 px * 72 = 14400 B
    float* nm = (float*)(smem + 35136);  // 64
    float* nr = nm + 64;                 // 64

    int tid = threadIdx.x;
    int gw = (H + 7) >> 3;
    int by = bx / gw, bxx = bx - by * gw;
    int y0 = by * 8, x0 = bxx * 8;
    int w = tid >> 6, lane = tid & 63;
    int n = lane & 15, q = lane >> 4;

    if (nrm) {
        if (tid < 64) {
            float s = cload(&sraw[tid]), s2 = cload(&sraw[64 + tid]);
            float mean = s * (1.f / 40000.f);
            float var = s2 * (1.f / 40000.f) - mean * mean;
            nm[tid] = mean;
            nr[tid] = rsqrtf(var + 1e-5f);
        }
        __syncthreads();
    }

    // stage 12x12 halo x 64ch bf16 HWC
    for (int i = tid; i < 2304; i += 256) {
        int px = i >> 4, c4 = (i & 15) * 4;
        int yy = px / 12, xx = px - yy * 12;
        int gy = y0 - 2 + yy, gx = x0 - 2 + xx;
        ushort4 v = {0, 0, 0, 0};
        if (gy >= 0 && gy < H && gx >= 0 && gx < H) {
            int off = ((gy * H + gx) << 6) + c4;
            if (nrm) {
                ushort4 a = chload4(&in[off]);
                ushort4 b = chload4(&nskip[off]);
                v.x = f2bf((b2f(a.x) - nm[c4 + 0]) * nr[c4 + 0] + b2f(b.x));
                v.y = f2bf((b2f(a.y) - nm[c4 + 1]) * nr[c4 + 1] + b2f(b.y));
                v.z = f2bf((b2f(a.z) - nm[c4 + 2]) * nr[c4 + 2] + b2f(b.z));
                v.w = f2bf((b2f(a.w) - nm[c4 + 3]) * nr[c4 + 3] + b2f(b.w));
            } else {
                v = chload4(&in[off]);
            }
        }
        *(ushort4*)&xin[px * 72 + c4] = v;
    }
    __syncthreads();

    // ---- conv1: 10x10 intermediate, 2 rounds of 4 wave-tiles ----
    const bhalf8* w1 = (const bhalf8*)wp1;
#pragma unroll 1
    for (int r = 0; r < 2; ++r) {
        int t = w + 4 * r;
        int px = t * 16 + n;
        bool val = px < 100;
        int pc = val ? px : 0;
        int yy = pc / 10, xx = pc - yy * 10;

        f32x4 acc[4];
#pragma unroll
        for (int m = 0; m < 4; ++m) acc[m] = (f32x4){0.f, 0.f, 0.f, 0.f};

        bhalf8 a0 = w1[0 * 64 + lane];
        bhalf8 a1 = w1[1 * 64 + lane];
        bhalf8 a2 = w1[2 * 64 + lane];
        bhalf8 a3 = w1[3 * 64 + lane];
        bhalf8 bb = *(const bhalf8*)&xin[(yy * 12 + xx) * 72 + q * 8];

#pragma unroll 1
        for (int p = 0; p < 18; ++p) {
            bhalf8 na0, na1, na2, na3, nbb;
            if (p < 17) {
                int pn = p + 1;
                na0 = w1[(pn * 4 + 0) * 64 + lane];
                na1 = w1[(pn * 4 + 1) * 64 + lane];
                na2 = w1[(pn * 4 + 2) * 64 + lane];
                na3 = w1[(pn * 4 + 3) * 64 + lane];
                int tap = pn >> 1, ch = pn & 1;
                int dy = tap / 3, dx = tap - dy * 3;
                nbb = *(const bhalf8*)&xin[((yy + dy) * 12 + xx + dx) * 72 + ch * 32 + q * 8];
            }
            acc[0] = __builtin_amdgcn_mfma_f32_16x16x32_bf16(a0, bb, acc[0], 0, 0, 0);
            acc[1] = __builtin_amdgcn_mfma_f32_16x16x32_bf16(a1, bb, acc[1], 0, 0, 0);
            acc[2] = __builtin_amdgcn_mfma_f32_16x16x32_bf16(a2, bb, acc[2], 0, 0, 0);
            acc[3] = __builtin_amdgcn_mfma_f32_16x16x32_bf16(a3, bb, acc[3], 0, 0, 0);
            a0 = na0; a1 = na1; a2 = na2; a3 = na3; bb = nbb;
        }

        int iy = y0 - 1 + yy, ix = x0 - 1 + xx;
        bool ok = val && iy >= 0 && iy < H && ix >= 0 && ix < H;
        if (val) {
#pragma unroll
            for (int m = 0; m < 4; ++m) {
                ushort4 o = {0, 0, 0, 0};
                if (ok) {
                    o.x = f2bf(fmaxf(acc[m][0], 0.f));
                    o.y = f2bf(fmaxf(acc[m][1], 0.f));
                    o.z = f2bf(fmaxf(acc[m][2], 0.f));
                    o.w = f2bf(fmaxf(acc[m][3], 0.f));
                }
                *(ushort4*)&ilds[px * 72 + m * 16 + q * 4] = o;
            }
        }
    }
    __syncthreads();

    // ---- conv2: 8x8 output from ilds ----
    f32x4 acc[4];
#pragma unroll
    for (int m = 0; m < 4; ++m) acc[m] = (f32x4){0.f, 0.f, 0.f, 0.f};
    const bhalf8* w2 = (const bhalf8*)wp2;
    int sy = 2 * w + (n >> 3), sx = n & 7;

    bhalf8 a0 = w2[0 * 64 + lane];
    bhalf8 a1 = w2[1 * 64 + lane];
    bhalf8 a2 = w2[2 * 64 + lane];
    bhalf8 a3 = w2[3 * 64 + lane];
    bhalf8 bb = *(const bhalf8*)&ilds[(sy * 10 + sx) * 72 + q * 8];

#pragma unroll 1
    for (int p = 0; p < 18; ++p) {
        bhalf8 na0, na1, na2, na3, nbb;
        if (p < 17) {
            int pn = p + 1;
            na0 = w2[(pn * 4 + 0) * 64 + lane];
            na1 = w2[(pn * 4 + 1) * 64 + lane];
            na2 = w2[(pn * 4 + 2) * 64 + lane];
            na3 = w2[(pn * 4 + 3) * 64 + lane];
            int tap = pn >> 1, ch = pn & 1;
            int dy = tap / 3, dx = tap - dy * 3;
            nbb = *(const bhalf8*)&ilds[((sy + dy) * 10 + sx + dx) * 72 + ch * 32 + q * 8];
        }
        acc[0] = __builtin_amdgcn_mfma_f32_16x16x32_bf16(a0, bb, acc[0], 0, 0, 0);
        acc[1] = __builtin_amdgcn_mfma_f32_16x16x32_bf16(a1, bb, acc[1], 0, 0, 0);
        acc[2] = __builtin_amdgcn_mfma_f32_16x16x32_bf16(a2, bb, acc[2], 0, 0, 0);
        acc[3] = __builtin_amdgcn_mfma_f32_16x16x32_bf16(a3, bb, acc[3], 0, 0, 0);
        a0 = na0; a1 = na1; a2 = na2; a3 = na3; bb = nbb;
    }

    // ---- residual from staged input + relu, store ----
    int gy = y0 + sy, gx = x0 + sx;
    if (gy < H && gx < H) {
        int base = (gy * H + gx) << 6;
#pragma unroll
        for (int m = 0; m < 4; ++m) {
            int oc0 = m * 16 + q * 4;
            ushort4 xr = *(const ushort4*)&xin[((sy + 2) * 12 + sx + 2) * 72 + oc0];
            float v0 = fmaxf(acc[m][0] + b2f(xr.x), 0.f);
            float v1 = fmaxf(acc[m][1] + b2f(xr.y), 0.f);
            float v2 = fmaxf(acc[m][2] + b2f(xr.z), 0.f);
            float v3 = fmaxf(acc[m][3] + b2f(xr.w), 0.f);
            if (final_) {
                int pix = gy * H + gx;
                outf[(oc0 + 0) * H * H + pix] = v0;
                outf[(oc0 + 1) * H * H + pix] = v1;
                outf[(oc0 + 2) * H * H + pix] = v2;
                outf[(oc0 + 3) * H * H + pix] = v3;
            } else {
                ushort4 o = { f2bf(v0), f2bf(v1), f2bf(v2), f2bf(v3) };
                chstore4(&outb[base + oc0], o);
            }
        }
    }
}

// ---------------------------------------------------------------------------
// Persistent megakernel: 7 phases, 6 grid barriers.
// ---------------------------------------------------------------------------
__global__ __launch_bounds__(256, 4) void gls_mega(
    const float* __restrict__ feats, const float* __restrict__ bev_emb,
    const u16* __restrict__ wprep,
    const float* __restrict__ params, const int* __restrict__ cnts,
    u16* __restrict__ R0h, u16* __restrict__ X0h,
    u16* __restrict__ X1h, u16* __restrict__ X2h,
    u16* __restrict__ Qr0h, u16* __restrict__ Sh,
    u16* __restrict__ Uh, u16* __restrict__ Y1h,
    float* __restrict__ out, int* __restrict__ barmem, float* __restrict__ sacc)
{
    __shared__ __align__(16) char smem[36352];
    int bid = blockIdx.x;
    int* leaf = barmem;
    int* root = barmem + 512;
    int* flag = barmem + 513;
    int ph = 0;

    // P1: render both stages (218 tiles), bf16 HWC outputs
    if (bid < 218) render_tile(bid, params, cnts, feats, R0h, Qr0h, smem);
    gbar(leaf, root, flag, ++ph);

    // P2: c0 (H100, +bev_emb) || c5 (H200 skip conv)
    if (bid < 169)
        conv_tile(bid, 100, R0h, wprep + 0 * WC, bev_emb, X0h, 0, 0, nullptr, smem);
    else if (bid < 794)
        conv_tile(bid - 169, 200, Qr0h, wprep + 5 * WC, nullptr, Sh, 0, 0, nullptr, smem);
    gbar(leaf, root, flag, ++ph);

    // P3/P4: H100 fused basic blocks
    if (bid < 169)
        bb_tile(bid, 100, X0h, wprep + 1 * WC, wprep + 2 * WC, X1h,
                nullptr, 0, 0, nullptr, nullptr, smem);
    gbar(leaf, root, flag, ++ph);
    if (bid < 169)
        bb_tile(bid, 100, X1h, wprep + 3 * WC, wprep + 4 * WC, X2h,
                nullptr, 0, 0, nullptr, nullptr, smem);
    gbar(leaf, root, flag, ++ph);

    // P5: upconv (LDS bilinear) + instance-norm stats
    if (bid < 625)
        conv_tile(bid, 200, X2h, wprep + 6 * WC, nullptr, Uh, 1, 1, sacc, smem);
    gbar(leaf, root, flag, ++ph);

    // P6: fused bb2 with instance-norm + skip staging
    if (bid < 625)
        bb_tile(bid, 200, Uh, wprep + 7 * WC, wprep + 8 * WC, Y1h,
                nullptr, 0, 1, Sh, sacc, smem);
    gbar(leaf, root, flag, ++ph);

    // P7: fused bb3, final epilogue writes d_out (f32 NCHW, cached)
    if (bid == 0 && threadIdx.x == 0)
        out[2560000] = (float)(cnts[0] + cnts[1]);
    if (bid < 625)
        bb_tile(bid, 200, Y1h, wprep + 9 * WC, wprep + 10 * WC, nullptr,
                out, 1, 0, nullptr, nullptr, smem);
}

// ---------------------------------------------------------------------------
extern "C" void kernel_launch(void* const* d_in, const int* in_sizes, int n_in,
                              void* d_out, int out_size, void* d_ws, size_t ws_size,
                              hipStream_t stream)
{
    const float* feats   = (const float*)d_in[0];
    const float* means   = (const float*)d_in[1];
    const float* cov6    = (const float*)d_in[2];
    const float* opac    = (const float*)d_in[3];
    const float* bev_emb = (const float*)d_in[4];
    const float* conv1_w = (const float*)d_in[5];
    const float* blk_w   = (const float*)d_in[6];
    const float* up_w    = (const float*)d_in[7];
    float* out = (float*)d_out;
    float* ws = (float*)d_ws;

    float* P      = ws;                          // 49152 floats
    int*   cnts   = (int*)(ws + 49152);
    int*   barmem = (int*)(ws + 49280);          // 520 ints
    float* sacc   = ws + 49856;                  // 128 floats
    u16*   wprep  = (u16*)(ws + 50176);          // 11*36864 u16

    u16* R0h  = (u16*)(ws + 262144);             // H100 bf16 HWC (640000 u16)
    u16* X0h  = (u16*)(ws + 589824);
    u16* X1h  = (u16*)(ws + 917504);
    u16* X2h  = (u16*)(ws + 1245184);
    u16* Qr0h = (u16*)(ws + 1572864);            // H200 bf16 HWC (2560000 u16)
    u16* Sh   = (u16*)(ws + 2883584);
    u16* Uh   = (u16*)(ws + 4194304);
    u16* Y1h  = (u16*)(ws + 5505024);

    gls_init<<<201, 256, 0, stream>>>(conv1_w, blk_w, up_w, wprep,
                                      means, cov6, opac, P, cnts, barmem, sacc);
    gls_mega<<<NBLK, 256, 0, stream>>>(feats, bev_emb, wprep, P, cnts,
                                       R0h, X0h, X1h, X2h, Qr0h, Sh, Uh, Y1h,
                                       out, barmem, sacc);
    (void)in_sizes; (void)n_in; (void)out_size; (void)ws_size;
}

// Round 9
// 269.151 us; speedup vs baseline: 8.8994x; 1.0466x over previous
//
#include <hip/hip_runtime.h>
#include <math.h>

#define G_N 2048
#define CCH 256
#define PSTR 12   // {u,v,A,B,C,op,pthr,gid, rx,ry, pad,pad}
#define NBLK 1024
#define WC (64 * 64 * 9)

typedef short bhalf8 __attribute__((ext_vector_type(8)));
typedef float f32x4 __attribute__((ext_vector_type(4)));
typedef unsigned short u16;

__device__ __forceinline__ u16 f2bf(float f) {
    unsigned u = __float_as_uint(f);
    unsigned r = (u + 0x7fffu + ((u >> 16) & 1u)) >> 16;
    return (u16)r;
}
__device__ __forceinline__ float b2f(u16 h) {
    return __uint_as_float((unsigned)h << 16);
}

// Coherent 8B ops (agent scope -> sc0 sc1: bypass L1/L2, served at the
// coherent point). Cross-phase traffic inside the persistent kernel.
__device__ __forceinline__ ushort4 chload4(const u16* p) {
    unsigned long long u = __hip_atomic_load((const unsigned long long*)p,
        __ATOMIC_RELAXED, __HIP_MEMORY_SCOPE_AGENT);
    union { unsigned long long u; ushort4 s; } x; x.u = u;
    return x.s;
}
__device__ __forceinline__ void chstore4(u16* p, ushort4 v) {
    union { unsigned long long u; ushort4 s; } x; x.s = v;
    __hip_atomic_store((unsigned long long*)p, x.u,
                       __ATOMIC_RELAXED, __HIP_MEMORY_SCOPE_AGENT);
}
__device__ __forceinline__ void cstore8(float* p, float a, float b) {
    union { unsigned long long u; float f[2]; } x;
    x.f[0] = a; x.f[1] = b;
    __hip_atomic_store((unsigned long long*)p, x.u,
                       __ATOMIC_RELAXED, __HIP_MEMORY_SCOPE_AGENT);
}
__device__ __forceinline__ float cload(const float* p) {
    return __hip_atomic_load(p, __ATOMIC_RELAXED, __HIP_MEMORY_SCOPE_AGENT);
}

// Fence-free grid barrier (validated r6-r8); s_sleep(16) backoff so the
// 1023 polling waves can't starve the releasing store (r8 outlier fix).
__device__ __forceinline__ void gbar(int* leaf, int* root, int* flag, int phase) {
    asm volatile("s_waitcnt vmcnt(0) lgkmcnt(0)" ::: "memory");
    __syncthreads();
    if (threadIdx.x == 0) {
        int g = blockIdx.x >> 5;
        int old = atomicAdd(&leaf[g * 16], 1);
        if ((old & 31) == 31) {
            int o2 = atomicAdd(root, 1);
            if ((o2 & 31) == 31)
                __hip_atomic_store(flag, phase, __ATOMIC_RELAXED,
                                   __HIP_MEMORY_SCOPE_AGENT);
        }
        while (__hip_atomic_load(flag, __ATOMIC_RELAXED,
                                 __HIP_MEMORY_SCOPE_AGENT) < phase)
            __builtin_amdgcn_s_sleep(16);
    }
    __syncthreads();
    asm volatile("" ::: "memory");
}

// ---------------------------------------------------------------------------
// Render one 8x8 tile. Wave w owns channels [w*16, w*16+16); lane = pixel.
// All 4 waves compute bitwise-identical alpha/T chains (same inputs).
// Output bf16 HWC via LDS-bounce + coalesced coherent 8B stores.
// ---------------------------------------------------------------------------
__device__ __forceinline__ void render_tile(
    int unit, const float* __restrict__ params, const int* __restrict__ counts,
    const float* __restrict__ feats, u16* __restrict__ out0,
    u16* __restrict__ out1, char* smem)
{
    int s = (unit < 169) ? 0 : 1;
    int t = (s == 0) ? unit : unit - 169;
    int tw = (s == 0) ? 13 : 25;
    int bxx = t % tw, byy = t / tw;
    int H = 100 << s;
    const float* P = params + s * G_N * PSTR;
    u16* out = s ? out1 : out0;
    int cnt = counts[s];

    float* raw = (float*)smem;
    float* cmp = raw + CCH * PSTR;
    int* s_wsum = (int*)(smem + 24576);

    int tid = threadIdx.x;
    int w = tid >> 6, lane = tid & 63;
    int pxl = lane & 7, pyl = lane >> 3;
    int x0 = bxx * 8, y0 = byy * 8;
    int px = x0 + pxl, py = y0 + pyl;
    bool active = (px < H) && (py < H);
    float fx = (float)px, fy = (float)py;
    float tx0 = (float)x0, tx1 = (float)min(H - 1, x0 + 7);
    float ty0 = (float)y0, ty1 = (float)min(H - 1, y0 + 7);

    f32x4 acc[4];
#pragma unroll
    for (int k = 0; k < 4; ++k) acc[k] = (f32x4){0.f, 0.f, 0.f, 0.f};
    float T = 1.f;

    for (int base = 0; base < cnt; base += CCH) {
        int anyalive = __syncthreads_or((int)(active && T > 1e-6f));
        if (!anyalive) break;
        int n = min(CCH, cnt - base);
        for (int i = tid; i < n * 3; i += 256)
            ((float4*)raw)[i] = ((const float4*)(P + base * PSTR))[i];
        __syncthreads();
        bool pass = false;
        if (tid < n) {
            float u = raw[tid * PSTR + 0], v = raw[tid * PSTR + 1];
            float rx = raw[tid * PSTR + 8], ry = raw[tid * PSTR + 9];
            pass = (u + rx >= tx0) && (u - rx <= tx1) &&
                   (v + ry >= ty0) && (v - ry <= ty1);
        }
        unsigned long long bal = __ballot(pass);
        int prefix = __popcll(bal & ((1ull << lane) - 1ull));
        if (lane == 0) s_wsum[w] = __popcll(bal);
        __syncthreads();
        int woff = 0;
        for (int k = 0; k < 4; ++k) if (k < w) woff += s_wsum[k];
        if (pass) {
            float4* dst = (float4*)(cmp + (woff + prefix) * PSTR);
            const float4* src = (const float4*)(raw + tid * PSTR);
            dst[0] = src[0]; dst[1] = src[1]; dst[2] = src[2];
        }
        __syncthreads();
        int nc = s_wsum[0] + s_wsum[1] + s_wsum[2] + s_wsum[3];
        if (active && T > 1e-6f) {
            for (int j = 0; j < nc; ++j) {
                float4 q0 = *(const float4*)(cmp + j * PSTR);
                float4 q1 = *(const float4*)(cmp + j * PSTR + 4);
                float dx = q0.x - fx, dy = q0.y - fy;
                float power = -0.5f * (q0.z * dx * dx + q1.x * dy * dy) - q0.w * dx * dy;
                if (power <= 0.f && power >= q1.z) {
                    float alpha = fminf(q1.y * __expf(power), 0.99f);
                    float wgt = alpha * T;
                    const f32x4* f4 = (const f32x4*)(feats + __float_as_int(q1.w) * 64) + w * 4;
#pragma unroll
                    for (int k = 0; k < 4; ++k) {
                        f32x4 fv = f4[k];
                        acc[k][0] = fmaf(wgt, fv[0], acc[k][0]);
                        acc[k][1] = fmaf(wgt, fv[1], acc[k][1]);
                        acc[k][2] = fmaf(wgt, fv[2], acc[k][2]);
                        acc[k][3] = fmaf(wgt, fv[3], acc[k][3]);
                    }
                    T *= (1.f - alpha);
                }
            }
        }
    }

    // LDS-bounce epilogue: 64 px x 64 ch, then contiguous bf16 HWC stores
    __syncthreads();
    float* shf = (float*)smem;   // 64*68 f32 (raw/cmp dead)
#pragma unroll
    for (int k = 0; k < 4; ++k)
        *(float4*)&shf[lane * 68 + w * 16 + k * 4] =
            (float4){acc[k][0], acc[k][1], acc[k][2], acc[k][3]};
    __syncthreads();
    for (int j = tid; j < 1024; j += 256) {
        int lp = j >> 4, c4 = (j & 15) * 4;
        int gy = y0 + (lp >> 3), gx = x0 + (lp & 7);
        if (gy < H && gx < H) {
            float4 v = *(float4*)&shf[lp * 68 + c4];
            ushort4 o = { f2bf(v.x), f2bf(v.y), f2bf(v.z), f2bf(v.w) };
            chstore4(&out[((gy * H + gx) << 6) + c4], o);
        }
    }
}

// ---------------------------------------------------------------------------
// Single MFMA conv3x3 tile (8x8 px x 64 oc). bf16 HWC coherent IO.
// bev: epilogue += bev_emb (f32 cached input). ups: bilinear via LDS tile.
// dostats: per-channel sum/sumsq into sacc.
// ---------------------------------------------------------------------------
__device__ __forceinline__ void conv_tile(
    int bx, int H, const u16* __restrict__ in, const u16* __restrict__ wp,
    const float* __restrict__ bev, u16* __restrict__ outb,
    int ups, int dostats, float* __restrict__ sacc, char* smem)
{
    u16* xlds = (u16*)smem;                      // 100*72*2 = 14400 B
    u16* fin  = (u16*)(smem + 14400);            // 64*68*2 (ups only)
    float* red = (float*)(smem + 16384 + 8704);  // 512 f

    int tid = threadIdx.x;
    int gw = (H + 7) >> 3;
    int by = bx / gw, bxx = bx - by * gw;
    int y0 = by * 8, x0 = bxx * 8;
    int w = tid >> 6, lane = tid & 63;
    int n = lane & 15, q = lane >> 4;
    int Hh = H >> 1;
    int oy = (y0 >> 1) - 2, ox = (x0 >> 1) - 2;

    if (ups) {
        for (int i = tid; i < 1024; i += 256) {
            int px = i >> 4, c4 = (i & 15) * 4;
            int iy = px >> 3, ix = px & 7;
            int gyi = oy + iy, gxi = ox + ix;
            ushort4 v = {0, 0, 0, 0};
            if (gyi >= 0 && gyi < Hh && gxi >= 0 && gxi < Hh)
                v = chload4(&in[((gyi * Hh + gxi) << 6) + c4]);
            *(ushort4*)&fin[px * 68 + c4] = v;
        }
        __syncthreads();
    }

    for (int i = tid; i < 1600; i += 256) {
        int px = i >> 4, c4 = (i & 15) * 4;
        int yy = px / 10, xx = px - yy * 10;
        int gy = y0 - 1 + yy, gx = x0 - 1 + xx;
        ushort4 v = {0, 0, 0, 0};
        if (gy >= 0 && gy < H && gx >= 0 && gx < H) {
            if (ups) {
                int yi = gy >> 1, xi = gx >> 1;
                int yb = (gy & 1) ? min(yi + 1, Hh - 1) : max(yi - 1, 0);
                int xb = (gx & 1) ? min(xi + 1, Hh - 1) : max(xi - 1, 0);
                int t0 = yi - oy, t1 = xi - ox, t2 = yb - oy, t3 = xb - ox;
                ushort4 f00 = *(const ushort4*)&fin[(t0 * 8 + t1) * 68 + c4];
                ushort4 f01 = *(const ushort4*)&fin[(t0 * 8 + t3) * 68 + c4];
                ushort4 f10 = *(const ushort4*)&fin[(t2 * 8 + t1) * 68 + c4];
                ushort4 f11 = *(const ushort4*)&fin[(t2 * 8 + t3) * 68 + c4];
                v.x = f2bf(0.5625f * b2f(f00.x) + 0.1875f * (b2f(f01.x) + b2f(f10.x)) + 0.0625f * b2f(f11.x));
                v.y = f2bf(0.5625f * b2f(f00.y) + 0.1875f * (b2f(f01.y) + b2f(f10.y)) + 0.0625f * b2f(f11.y));
                v.z = f2bf(0.5625f * b2f(f00.z) + 0.1875f * (b2f(f01.z) + b2f(f10.z)) + 0.0625f * b2f(f11.z));
                v.w = f2bf(0.5625f * b2f(f00.w) + 0.1875f * (b2f(f01.w) + b2f(f10.w)) + 0.0625f * b2f(f11.w));
            } else {
                v = chload4(&in[((gy * H + gx) << 6) + c4]);
            }
        }
        *(ushort4*)&xlds[px * 72 + c4] = v;
    }
    __syncthreads();

    f32x4 acc[4];
#pragma unroll
    for (int m = 0; m < 4; ++m) acc[m] = (f32x4){0.f, 0.f, 0.f, 0.f};
    const bhalf8* wp8 = (const bhalf8*)wp;
    int sy = 2 * w + (n >> 3), sx = n & 7;

    bhalf8 a0 = wp8[0 * 64 + lane];
    bhalf8 a1 = wp8[1 * 64 + lane];
    bhalf8 a2 = wp8[2 * 64 + lane];
    bhalf8 a3 = wp8[3 * 64 + lane];
    bhalf8 bb = *(const bhalf8*)&xlds[(sy * 10 + sx) * 72 + q * 8];

#pragma unroll 1
    for (int p = 0; p < 18; ++p) {
        bhalf8 na0, na1, na2, na3, nbb;
        if (p < 17) {
            int pn = p + 1;
            na0 = wp8[(pn * 4 + 0) * 64 + lane];
            na1 = wp8[(pn * 4 + 1) * 64 + lane];
            na2 = wp8[(pn * 4 + 2) * 64 + lane];
            na3 = wp8[(pn * 4 + 3) * 64 + lane];
            int tap = pn >> 1, ch = pn & 1;
            int dy = tap / 3, dx = tap - dy * 3;
            nbb = *(const bhalf8*)&xlds[((sy + dy) * 10 + sx + dx) * 72 + ch * 32 + q * 8];
        }
        acc[0] = __builtin_amdgcn_mfma_f32_16x16x32_bf16(a0, bb, acc[0], 0, 0, 0);
        acc[1] = __builtin_amdgcn_mfma_f32_16x16x32_bf16(a1, bb, acc[1], 0, 0, 0);
        acc[2] = __builtin_amdgcn_mfma_f32_16x16x32_bf16(a2, bb, acc[2], 0, 0, 0);
        acc[3] = __builtin_amdgcn_mfma_f32_16x16x32_bf16(a3, bb, acc[3], 0, 0, 0);
        a0 = na0; a1 = na1; a2 = na2; a3 = na3; bb = nbb;
    }

    int gy = y0 + sy, gx = x0 + sx;
    if (gy < H && gx < H) {
        int base = (gy * H + gx) << 6;
#pragma unroll
        for (int m = 0; m < 4; ++m) {
            int oc0 = m * 16 + q * 4;
            float v0 = acc[m][0], v1 = acc[m][1], v2 = acc[m][2], v3 = acc[m][3];
            if (bev) {
                float4 av = *(const float4*)&bev[base + oc0];
                v0 += av.x; v1 += av.y; v2 += av.z; v3 += av.w;
            }
            ushort4 o = { f2bf(v0), f2bf(v1), f2bf(v2), f2bf(v3) };
            chstore4(&outb[base + oc0], o);
        }
    }

    if (dostats) {
#pragma unroll
        for (int m = 0; m < 4; ++m)
#pragma unroll
            for (int r = 0; r < 4; ++r) {
                float v = acc[m][r];
                float s = v, s2 = v * v;
#pragma unroll
                for (int d = 1; d < 16; d <<= 1) {
                    s += __shfl_xor(s, d, 64);
                    s2 += __shfl_xor(s2, d, 64);
                }
                if (n == 0) {
                    int oc = m * 16 + q * 4 + r;
                    red[w * 128 + oc] = s;
                    red[w * 128 + 64 + oc] = s2;
                }
            }
        __syncthreads();
        if (tid < 128) {
            float t = red[tid] + red[128 + tid] + red[256 + tid] + red[384 + tid];
            atomicAdd(&sacc[tid], t);
        }
    }
}

// ---------------------------------------------------------------------------
// FUSED basic block: out = relu(x + conv2(relu(conv1(x)))). conv1 -> 10x10
// LDS intermediate, conv2 from LDS, residual from staged tile.
// nrm: staging computes x = instnorm(in)+nskip. final_: f32 NCHW to outf.
// ---------------------------------------------------------------------------
__device__ __forceinline__ void bb_tile(
    int bx, int H, const u16* __restrict__ in,
    const u16* __restrict__ wp1, const u16* __restrict__ wp2,
    u16* __restrict__ outb, float* __restrict__ outf, int final_,
    int nrm, const u16* __restrict__ nskip, const float* __restrict__ sraw,
    char* smem)
{
    u16* xin  = (u16*)smem;              // 144*72*2 = 20736 B
    u16* ilds = (u16*)(smem + 20736);    // 100*72*2 = 14400 B
    float* nm = (float*)(smem + 35136);  // 64
    float* nr = nm + 64;                 // 64

    int tid = threadIdx.x;
    int gw = (H + 7) >> 3;
    int by = bx / gw, bxx = bx - by * gw;
    int y0 = by * 8, x0 = bxx * 8;
    int w = tid >> 6, lane = tid & 63;
    int n = lane & 15, q = lane >> 4;

    if (nrm) {
        if (tid < 64) {
            float s = cload(&sraw[tid]), s2 = cload(&sraw[64 + tid]);
            float mean = s * (1.f / 40000.f);
            float var = s2 * (1.f / 40000.f) - mean * mean;
            nm[tid] = mean;
            nr[tid] = rsqrtf(var + 1e-5f);
        }
        __syncthreads();
    }

    for (int i = tid; i < 2304; i += 256) {
        int px = i >> 4, c4 = (i & 15) * 4;
        int yy = px / 12, xx = px - yy * 12;
        int gy = y0 - 2 + yy, gx = x0 - 2 + xx;
        ushort4 v = {0, 0, 0, 0};
        if (gy >= 0 && gy < H && gx >= 0 && gx < H) {
            int off = ((gy * H + gx) << 6) + c4;
            if (nrm) {
                ushort4 a = chload4(&in[off]);
                ushort4 b = chload4(&nskip[off]);
                v.x = f2bf((b2f(a.x) - nm[c4 + 0]) * nr[c4 + 0] + b2f(b.x));
                v.y = f2bf((b2f(a.y) - nm[c4 + 1]) * nr[c4 + 1] + b2f(b.y));
                v.z = f2bf((b2f(a.z) - nm[c4 + 2]) * nr[c4 + 2] + b2f(b.z));
                v.w = f2bf((b2f(a.w) - nm[c4 + 3]) * nr[c4 + 3] + b2f(b.w));
            } else {
                v = chload4(&in[off]);
            }
        }
        *(ushort4*)&xin[px * 72 + c4] = v;
    }
    __syncthreads();

    const bhalf8* w1 = (const bhalf8*)wp1;
#pragma unroll 1
    for (int r = 0; r < 2; ++r) {
        int t = w + 4 * r;
        int px = t * 16 + n;
        bool val = px < 100;
        int pc = val ? px : 0;
        int yy = pc / 10, xx = pc - yy * 10;

        f32x4 acc[4];
#pragma unroll
        for (int m = 0; m < 4; ++m) acc[m] = (f32x4){0.f, 0.f, 0.f, 0.f};

        bhalf8 a0 = w1[0 * 64 + lane];
        bhalf8 a1 = w1[1 * 64 + lane];
        bhalf8 a2 = w1[2 * 64 + lane];
        bhalf8 a3 = w1[3 * 64 + lane];
        bhalf8 bb = *(const bhalf8*)&xin[(yy * 12 + xx) * 72 + q * 8];

#pragma unroll 1
        for (int p = 0; p < 18; ++p) {
            bhalf8 na0, na1, na2, na3, nbb;
            if (p < 17) {
                int pn = p + 1;
                na0 = w1[(pn * 4 + 0) * 64 + lane];
                na1 = w1[(pn * 4 + 1) * 64 + lane];
                na2 = w1[(pn * 4 + 2) * 64 + lane];
                na3 = w1[(pn * 4 + 3) * 64 + lane];
                int tap = pn >> 1, ch = pn & 1;
                int dy = tap / 3, dx = tap - dy * 3;
                nbb = *(const bhalf8*)&xin[((yy + dy) * 12 + xx + dx) * 72 + ch * 32 + q * 8];
            }
            acc[0] = __builtin_amdgcn_mfma_f32_16x16x32_bf16(a0, bb, acc[0], 0, 0, 0);
            acc[1] = __builtin_amdgcn_mfma_f32_16x16x32_bf16(a1, bb, acc[1], 0, 0, 0);
            acc[2] = __builtin_amdgcn_mfma_f32_16x16x32_bf16(a2, bb, acc[2], 0, 0, 0);
            acc[3] = __builtin_amdgcn_mfma_f32_16x16x32_bf16(a3, bb, acc[3], 0, 0, 0);
            a0 = na0; a1 = na1; a2 = na2; a3 = na3; bb = nbb;
        }

        int iy = y0 - 1 + yy, ix = x0 - 1 + xx;
        bool ok = val && iy >= 0 && iy < H && ix >= 0 && ix < H;
        if (val) {
#pragma unroll
            for (int m = 0; m < 4; ++m) {
                ushort4 o = {0, 0, 0, 0};
                if (ok) {
                    o.x = f2bf(fmaxf(acc[m][0], 0.f));
                    o.y = f2bf(fmaxf(acc[m][1], 0.f));
                    o.z = f2bf(fmaxf(acc[m][2], 0.f));
                    o.w = f2bf(fmaxf(acc[m][3], 0.f));
                }
                *(ushort4*)&ilds[px * 72 + m * 16 + q * 4] = o;
            }
        }
    }
    __syncthreads();

    f32x4 acc[4];
#pragma unroll
    for (int m = 0; m < 4; ++m) acc[m] = (f32x4){0.f, 0.f, 0.f, 0.f};
    const bhalf8* w2 = (const bhalf8*)wp2;
    int sy = 2 * w + (n >> 3), sx = n & 7;

    bhalf8 a0 = w2[0 * 64 + lane];
    bhalf8 a1 = w2[1 * 64 + lane];
    bhalf8 a2 = w2[2 * 64 + lane];
    bhalf8 a3 = w2[3 * 64 + lane];
    bhalf8 bb = *(const bhalf8*)&ilds[(sy * 10 + sx) * 72 + q * 8];

#pragma unroll 1
    for (int p = 0; p < 18; ++p) {
        bhalf8 na0, na1, na2, na3, nbb;
        if (p < 17) {
            int pn = p + 1;
            na0 = w2[(pn * 4 + 0) * 64 + lane];
            na1 = w2[(pn * 4 + 1) * 64 + lane];
            na2 = w2[(pn * 4 + 2) * 64 + lane];
            na3 = w2[(pn * 4 + 3) * 64 + lane];
            int tap = pn >> 1, ch = pn & 1;
            int dy = tap / 3, dx = tap - dy * 3;
            nbb = *(const bhalf8*)&ilds[((sy + dy) * 10 + sx + dx) * 72 + ch * 32 + q * 8];
        }
        acc[0] = __builtin_amdgcn_mfma_f32_16x16x32_bf16(a0, bb, acc[0], 0, 0, 0);
        acc[1] = __builtin_amdgcn_mfma_f32_16x16x32_bf16(a1, bb, acc[1], 0, 0, 0);
        acc[2] = __builtin_amdgcn_mfma_f32_16x16x32_bf16(a2, bb, acc[2], 0, 0, 0);
        acc[3] = __builtin_amdgcn_mfma_f32_16x16x32_bf16(a3, bb, acc[3], 0, 0, 0);
        a0 = na0; a1 = na1; a2 = na2; a3 = na3; bb = nbb;
    }

    int gy = y0 + sy, gx = x0 + sx;
    if (gy < H && gx < H) {
        int base = (gy * H + gx) << 6;
#pragma unroll
        for (int m = 0; m < 4; ++m) {
            int oc0 = m * 16 + q * 4;
            ushort4 xr = *(const ushort4*)&xin[((sy + 2) * 12 + sx + 2) * 72 + oc0];
            float v0 = fmaxf(acc[m][0] + b2f(xr.x), 0.f);
            float v1 = fmaxf(acc[m][1] + b2f(xr.y), 0.f);
            float v2 = fmaxf(acc[m][2] + b2f(xr.z), 0.f);
            float v3 = fmaxf(acc[m][3] + b2f(xr.w), 0.f);
            if (final_) {
                int pix = gy * H + gx;
                outf[(oc0 + 0) * H * H + pix] = v0;
                outf[(oc0 + 1) * H * H + pix] = v1;
                outf[(oc0 + 2) * H * H + pix] = v2;
                outf[(oc0 + 3) * H * H + pix] = v3;
            } else {
                ushort4 o = { f2bf(v0), f2bf(v1), f2bf(v2), f2bf(v3) };
                chstore4(&outb[base + oc0], o);
            }
        }
    }
}

// ---------------------------------------------------------------------------
// Single persistent megakernel: P0 precompute; P1 render||repack; P2..P7.
// ---------------------------------------------------------------------------
__global__ __launch_bounds__(256, 4) void gls_mega(
    const float* __restrict__ feats, const float* __restrict__ bev_emb,
    const float* __restrict__ conv1_w, const float* __restrict__ blk_w,
    const float* __restrict__ up_w, const float* __restrict__ means,
    const float* __restrict__ cov6, const float* __restrict__ opac,
    u16* __restrict__ wprep, float* __restrict__ params, int* __restrict__ cnts,
    u16* __restrict__ R0h, u16* __restrict__ X0h,
    u16* __restrict__ X1h, u16* __restrict__ X2h,
    u16* __restrict__ Qr0h, u16* __restrict__ Sh,
    u16* __restrict__ Uh, u16* __restrict__ Y1h,
    float* __restrict__ out, int* __restrict__ barmem, float* __restrict__ sacc)
{
    __shared__ __align__(16) char smem[36352];
    int bid = blockIdx.x;
    int tid = threadIdx.x;
    int* leaf = barmem;
    int* root = barmem + 512;
    int* flag = barmem + 513;
    int ph = 0;

    // ---- P0: splat precompute (blocks 0,1), coherent param stores ----
    if (bid < 2) {
        int s = bid;
        int* s_base = (int*)smem;
        int* s_wsum = s_base + 16;
        if (tid == 0) *s_base = 0;
        __syncthreads();
        float* P = params + s * G_N * PSTR;
        float H = (float)(100 << s);
        float sh = (float)(1 << s);
        for (int it = 0; it < G_N / 256; ++it) {
            int g = it * 256 + tid;
            float mx = means[g * 3 + 0], my = means[g * 3 + 1], mz = means[g * 3 + 2];
            float op = opac[g * 2 + s];
            bool mask = (mx >= -50.f && mx <= 50.f && my >= -50.f && my <= 50.f &&
                         mz >= -4.f && mz <= 4.f && op > 0.05f);
            unsigned long long bal = __ballot(mask);
            int lane = tid & 63, wid = tid >> 6;
            int prefix = __popcll(bal & ((1ull << lane) - 1ull));
            if (lane == 0) s_wsum[wid] = __popcll(bal);
            __syncthreads();
            int woff = 0;
            for (int w = 0; w < 4; ++w) if (w < wid) woff += s_wsum[w];
            int pos = *s_base + woff + prefix;
            if (mask) {
                float u = -sh * my + 0.5f * H;
                float v = -sh * mx + 0.5f * H;
                float a = sh * sh * cov6[g * 6 + 3] + 0.3f;
                float c = sh * sh * cov6[g * 6 + 0] + 0.3f;
                float bb = sh * sh * cov6[g * 6 + 1];
                float det = fmaxf(a * c - bb * bb, 1e-8f);
                float t = logf(255.f * op);
                float* Q = P + pos * PSTR;
                cstore8(&Q[0], u, v);
                cstore8(&Q[2], c / det, -bb / det);
                cstore8(&Q[4], a / det, op);
                cstore8(&Q[6], -t, __int_as_float(g));
                cstore8(&Q[8], sqrtf(2.f * t * a), sqrtf(2.f * t * c));
            }
            __syncthreads();
            if (tid == 0) *s_base += s_wsum[0] + s_wsum[1] + s_wsum[2] + s_wsum[3];
            __syncthreads();
        }
        if (tid == 0)
            __hip_atomic_store(&cnts[s], *s_base, __ATOMIC_RELAXED,
                               __HIP_MEMORY_SCOPE_AGENT);
    }
    gbar(leaf, root, flag, ++ph);

    // ---- P1: render (0..793) || weight repack (794..991), coherent stores ----
    if (bid < 794) {
        render_tile(bid, params, cnts, feats, R0h, Qr0h, smem);
    } else if (bid < 992) {
        int rb = bid - 794;
        int p = rb % 18, c = rb / 18;
        const float* src;
        if (c == 0) src = conv1_w;
        else if (c <= 4) src = blk_w + (c - 1) * WC;
        else if (c == 5) src = conv1_w + WC;
        else if (c == 6) src = up_w;
        else src = blk_w + (c - 3) * WC;
        int tap = p >> 1;
        int m = tid >> 6, lane = tid & 63;
        int oc = m * 16 + (lane & 15);
        int ci0 = (p & 1) * 32 + (lane >> 4) * 8;
        u16 v[8];
#pragma unroll
        for (int j = 0; j < 8; ++j)
            v[j] = f2bf(src[(oc * 64 + ci0 + j) * 9 + tap]);
        u16* dst = wprep + ((c * 18 + p) * 4 + m) * 64 * 8 + lane * 8;
        chstore4(dst, (ushort4){v[0], v[1], v[2], v[3]});
        chstore4(dst + 4, (ushort4){v[4], v[5], v[6], v[7]});
    }
    gbar(leaf, root, flag, ++ph);

    // ---- P2: c0 (H100, +bev_emb) || c5 (H200 skip conv) ----
    if (bid < 169)
        conv_tile(bid, 100, R0h, wprep + 0 * WC, bev_emb, X0h, 0, 0, nullptr, smem);
    else if (bid < 794)
        conv_tile(bid - 169, 200, Qr0h, wprep + 5 * WC, nullptr, Sh, 0, 0, nullptr, smem);
    gbar(leaf, root, flag, ++ph);

    // ---- P3/P4: H100 fused basic blocks ----
    if (bid < 169)
        bb_tile(bid, 100, X0h, wprep + 1 * WC, wprep + 2 * WC, X1h,
                nullptr, 0, 0, nullptr, nullptr, smem);
    gbar(leaf, root, flag, ++ph);
    if (bid < 169)
        bb_tile(bid, 100, X1h, wprep + 3 * WC, wprep + 4 * WC, X2h,
                nullptr, 0, 0, nullptr, nullptr, smem);
    gbar(leaf, root, flag, ++ph);

    // ---- P5: upconv (LDS bilinear) + instance-norm stats ----
    if (bid < 625)
        conv_tile(bid, 200, X2h, wprep + 6 * WC, nullptr, Uh, 1, 1, sacc, smem);
    gbar(leaf, root, flag, ++ph);

    // ---- P6: fused bb with instance-norm + skip staging ----
    if (bid < 625)
        bb_tile(bid, 200, Uh, wprep + 7 * WC, wprep + 8 * WC, Y1h,
                nullptr, 0, 1, Sh, sacc, smem);
    gbar(leaf, root, flag, ++ph);

    // ---- P7: fused bb, final epilogue writes d_out (f32 NCHW) ----
    if (bid == 0 && threadIdx.x == 0)
        out[2560000] = (float)(cnts[0] + cnts[1]);
    if (bid < 625)
        bb_tile(bid, 200, Y1h, wprep + 9 * WC, wprep + 10 * WC, nullptr,
                out, 1, 0, nullptr, nullptr, smem);
}

// ---------------------------------------------------------------------------
extern "C" void kernel_launch(void* const* d_in, const int* in_sizes, int n_in,
                              void* d_out, int out_size, void* d_ws, size_t ws_size,
                              hipStream_t stream)
{
    const float* feats   = (const float*)d_in[0];
    const float* means   = (const float*)d_in[1];
    const float* cov6    = (const float*)d_in[2];
    const float* opac    = (const float*)d_in[3];
    const float* bev_emb = (const float*)d_in[4];
    const float* conv1_w = (const float*)d_in[5];
    const float* blk_w   = (const float*)d_in[6];
    const float* up_w    = (const float*)d_in[7];
    float* out = (float*)d_out;
    float* ws = (float*)d_ws;

    float* P      = ws;                          // 49152 floats
    int*   cnts   = (int*)(ws + 49152);
    int*   barmem = (int*)(ws + 49280);          // 520 ints
    float* sacc   = ws + 49856;                  // 128 floats
    u16*   wprep  = (u16*)(ws + 50176);          // 11*36864 u16

    u16* R0h  = (u16*)(ws + 262144);             // H100 bf16 HWC
    u16* X0h  = (u16*)(ws + 589824);
    u16* X1h  = (u16*)(ws + 917504);
    u16* X2h  = (u16*)(ws + 1245184);
    u16* Qr0h = (u16*)(ws + 1572864);            // H200 bf16 HWC
    u16* Sh   = (u16*)(ws + 2883584);
    u16* Uh   = (u16*)(ws + 4194304);
    u16* Y1h  = (u16*)(ws + 5505024);

    // zero barrier counters + stats accumulators (graph-safe memset node)
    hipMemsetAsync(barmem, 0, (520 + 64 + 128) * 4, stream);
    gls_mega<<<NBLK, 256, 0, stream>>>(feats, bev_emb, conv1_w, blk_w, up_w,
                                       means, cov6, opac, wprep, P, cnts,
                                       R0h, X0h, X1h, X2h, Qr0h, Sh, Uh, Y1h,
                                       out, barmem, sacc);
    (void)in_sizes; (void)n_in; (void)out_size; (void)ws_size;
}

// Round 10
// 259.978 us; speedup vs baseline: 9.2134x; 1.0353x over previous
//
#include <hip/hip_runtime.h>
#include <math.h>

#define G_N 2048
#define CCH 256
#define PSTR 12   // {u,v,A,B,C,op,pthr,gid, rx,ry, pad,pad}
#define NBLK 1024
#define WC (64 * 64 * 9)

typedef short bhalf8 __attribute__((ext_vector_type(8)));
typedef float f32x4 __attribute__((ext_vector_type(4)));
typedef unsigned short u16;

__device__ __forceinline__ u16 f2bf(float f) {
    unsigned u = __float_as_uint(f);
    unsigned r = (u + 0x7fffu + ((u >> 16) & 1u)) >> 16;
    return (u16)r;
}
__device__ __forceinline__ float b2f(u16 h) {
    return __uint_as_float((unsigned)h << 16);
}

// Coherent stores (agent scope -> sc0 sc1: write past L2 to the memory-side
// IC). Consumers use NORMAL cached loads: each buffer is write-once-then-read
// with a grid barrier between, L2 is invalidated at kernel start, and the
// first-touch load misses L2 -> fetches fresh IC data. Pattern HW-validated
// in r9 (wprep/params: coherent store -> normal load, repeated passes).
__device__ __forceinline__ void chstore4(u16* p, ushort4 v) {
    union { unsigned long long u; ushort4 s; } x; x.s = v;
    __hip_atomic_store((unsigned long long*)p, x.u,
                       __ATOMIC_RELAXED, __HIP_MEMORY_SCOPE_AGENT);
}
__device__ __forceinline__ void cstore8(float* p, float a, float b) {
    union { unsigned long long u; float f[2]; } x;
    x.f[0] = a; x.f[1] = b;
    __hip_atomic_store((unsigned long long*)p, x.u,
                       __ATOMIC_RELAXED, __HIP_MEMORY_SCOPE_AGENT);
}
__device__ __forceinline__ float cload(const float* p) {
    return __hip_atomic_load(p, __ATOMIC_RELAXED, __HIP_MEMORY_SCOPE_AGENT);
}
__device__ __forceinline__ int iload(const int* p) {
    return __hip_atomic_load(p, __ATOMIC_RELAXED, __HIP_MEMORY_SCOPE_AGENT);
}

// Fence-free grid barrier (validated r6-r9), s_sleep(16) backoff.
__device__ __forceinline__ void gbar(int* leaf, int* root, int* flag, int phase) {
    asm volatile("s_waitcnt vmcnt(0) lgkmcnt(0)" ::: "memory");
    __syncthreads();
    if (threadIdx.x == 0) {
        int g = blockIdx.x >> 5;
        int old = atomicAdd(&leaf[g * 16], 1);
        if ((old & 31) == 31) {
            int o2 = atomicAdd(root, 1);
            if ((o2 & 31) == 31)
                __hip_atomic_store(flag, phase, __ATOMIC_RELAXED,
                                   __HIP_MEMORY_SCOPE_AGENT);
        }
        while (__hip_atomic_load(flag, __ATOMIC_RELAXED,
                                 __HIP_MEMORY_SCOPE_AGENT) < phase)
            __builtin_amdgcn_s_sleep(16);
    }
    __syncthreads();
    asm volatile("" ::: "memory");
}

// ---------------------------------------------------------------------------
// Render one 8x8 tile. Wave w owns channels [w*16,w*16+16); lane = pixel.
// No compaction: params slot = gaussian id; culled slots carry rx=ry=-1 so
// the bbox test rejects them (order-preserving by construction).
// ---------------------------------------------------------------------------
__device__ __forceinline__ void render_tile(
    int unit, const float* __restrict__ params,
    const float* __restrict__ feats, u16* __restrict__ out0,
    u16* __restrict__ out1, char* smem)
{
    int s = (unit < 169) ? 0 : 1;
    int t = (s == 0) ? unit : unit - 169;
    int tw = (s == 0) ? 13 : 25;
    int bxx = t % tw, byy = t / tw;
    int H = 100 << s;
    const float* P = params + s * G_N * PSTR;
    u16* out = s ? out1 : out0;

    float* raw = (float*)smem;
    float* cmp = raw + CCH * PSTR;
    int* s_wsum = (int*)(smem + 24576);

    int tid = threadIdx.x;
    int w = tid >> 6, lane = tid & 63;
    int x0 = bxx * 8, y0 = byy * 8;
    int px = x0 + (lane & 7), py = y0 + (lane >> 3);
    bool active = (px < H) && (py < H);
    float fx = (float)px, fy = (float)py;
    float tx0 = (float)x0, tx1 = (float)min(H - 1, x0 + 7);
    float ty0 = (float)y0, ty1 = (float)min(H - 1, y0 + 7);

    f32x4 acc[4];
#pragma unroll
    for (int k = 0; k < 4; ++k) acc[k] = (f32x4){0.f, 0.f, 0.f, 0.f};
    float T = 1.f;

    for (int base = 0; base < G_N; base += CCH) {
        int anyalive = __syncthreads_or((int)(active && T > 1e-6f));
        if (!anyalive) break;
        for (int i = tid; i < CCH * 3; i += 256)
            ((float4*)raw)[i] = ((const float4*)(P + base * PSTR))[i];
        __syncthreads();
        float u = raw[tid * PSTR + 0], v = raw[tid * PSTR + 1];
        float rx = raw[tid * PSTR + 8], ry = raw[tid * PSTR + 9];
        bool pass = (u + rx >= tx0) && (u - rx <= tx1) &&
                    (v + ry >= ty0) && (v - ry <= ty1);
        unsigned long long bal = __ballot(pass);
        int prefix = __popcll(bal & ((1ull << lane) - 1ull));
        if (lane == 0) s_wsum[w] = __popcll(bal);
        __syncthreads();
        int woff = 0;
        for (int k = 0; k < 4; ++k) if (k < w) woff += s_wsum[k];
        if (pass) {
            float4* dst = (float4*)(cmp + (woff + prefix) * PSTR);
            const float4* src = (const float4*)(raw + tid * PSTR);
            dst[0] = src[0]; dst[1] = src[1]; dst[2] = src[2];
        }
        __syncthreads();
        int nc = s_wsum[0] + s_wsum[1] + s_wsum[2] + s_wsum[3];
        if (active && T > 1e-6f) {
            for (int j = 0; j < nc; ++j) {
                float4 q0 = *(const float4*)(cmp + j * PSTR);
                float4 q1 = *(const float4*)(cmp + j * PSTR + 4);
                float dx = q0.x - fx, dy = q0.y - fy;
                float power = -0.5f * (q0.z * dx * dx + q1.x * dy * dy) - q0.w * dx * dy;
                if (power <= 0.f && power >= q1.z) {
                    float alpha = fminf(q1.y * __expf(power), 0.99f);
                    float wgt = alpha * T;
                    const f32x4* f4 = (const f32x4*)(feats + __float_as_int(q1.w) * 64) + w * 4;
#pragma unroll
                    for (int k = 0; k < 4; ++k) {
                        f32x4 fv = f4[k];
                        acc[k][0] = fmaf(wgt, fv[0], acc[k][0]);
                        acc[k][1] = fmaf(wgt, fv[1], acc[k][1]);
                        acc[k][2] = fmaf(wgt, fv[2], acc[k][2]);
                        acc[k][3] = fmaf(wgt, fv[3], acc[k][3]);
                    }
                    T *= (1.f - alpha);
                }
            }
        }
    }

    __syncthreads();
    float* shf = (float*)smem;   // 64*68 f32 (raw/cmp dead)
#pragma unroll
    for (int k = 0; k < 4; ++k)
        *(float4*)&shf[lane * 68 + w * 16 + k * 4] =
            (float4){acc[k][0], acc[k][1], acc[k][2], acc[k][3]};
    __syncthreads();
    for (int j = tid; j < 1024; j += 256) {
        int lp = j >> 4, c4 = (j & 15) * 4;
        int gy = y0 + (lp >> 3), gx = x0 + (lp & 7);
        if (gy < H && gx < H) {
            float4 v = *(float4*)&shf[lp * 68 + c4];
            ushort4 o = { f2bf(v.x), f2bf(v.y), f2bf(v.z), f2bf(v.w) };
            chstore4(&out[((gy * H + gx) << 6) + c4], o);
        }
    }
}

// ---------------------------------------------------------------------------
// MFMA conv3x3 tile (8x8 px x 64 oc). Cached loads, coherent stores.
// ---------------------------------------------------------------------------
__device__ __forceinline__ void conv_tile(
    int bx, int H, const u16* __restrict__ in, const u16* __restrict__ wp,
    const float* __restrict__ bev, u16* __restrict__ outb,
    int ups, int dostats, float* __restrict__ sacc, char* smem)
{
    u16* xlds = (u16*)smem;                      // 100*72*2 = 14400 B
    u16* fin  = (u16*)(smem + 14400);            // 64*72*2 = 9216 B (ups only)
    float* red = (float*)(smem + 25600);         // 512 f

    int tid = threadIdx.x;
    int gw = (H + 7) >> 3;
    int by = bx / gw, bxx = bx - by * gw;
    int y0 = by * 8, x0 = bxx * 8;
    int w = tid >> 6, lane = tid & 63;
    int n = lane & 15, q = lane >> 4;
    int Hh = H >> 1;
    int oy = (y0 >> 1) - 2, ox = (x0 >> 1) - 2;

    if (ups) {
        for (int i = tid; i < 512; i += 256) {
            int px = i >> 3, c8 = (i & 7) * 8;
            int iy = px >> 3, ix = px & 7;
            int gyi = oy + iy, gxi = ox + ix;
            uint4 v = {0, 0, 0, 0};
            if (gyi >= 0 && gyi < Hh && gxi >= 0 && gxi < Hh)
                v = *(const uint4*)&in[((gyi * Hh + gxi) << 6) + c8];
            *(uint4*)&fin[px * 72 + c8] = v;
        }
        __syncthreads();
        for (int i = tid; i < 1600; i += 256) {
            int px = i >> 4, c4 = (i & 15) * 4;
            int yy = px / 10, xx = px - yy * 10;
            int gy = y0 - 1 + yy, gx = x0 - 1 + xx;
            ushort4 v = {0, 0, 0, 0};
            if (gy >= 0 && gy < H && gx >= 0 && gx < H) {
                int yi = gy >> 1, xi = gx >> 1;
                int yb = (gy & 1) ? min(yi + 1, Hh - 1) : max(yi - 1, 0);
                int xb = (gx & 1) ? min(xi + 1, Hh - 1) : max(xi - 1, 0);
                int t0 = yi - oy, t1 = xi - ox, t2 = yb - oy, t3 = xb - ox;
                ushort4 f00 = *(const ushort4*)&fin[(t0 * 8 + t1) * 72 + c4];
                ushort4 f01 = *(const ushort4*)&fin[(t0 * 8 + t3) * 72 + c4];
                ushort4 f10 = *(const ushort4*)&fin[(t2 * 8 + t1) * 72 + c4];
                ushort4 f11 = *(const ushort4*)&fin[(t2 * 8 + t3) * 72 + c4];
                v.x = f2bf(0.5625f * b2f(f00.x) + 0.1875f * (b2f(f01.x) + b2f(f10.x)) + 0.0625f * b2f(f11.x));
                v.y = f2bf(0.5625f * b2f(f00.y) + 0.1875f * (b2f(f01.y) + b2f(f10.y)) + 0.0625f * b2f(f11.y));
                v.z = f2bf(0.5625f * b2f(f00.z) + 0.1875f * (b2f(f01.z) + b2f(f10.z)) + 0.0625f * b2f(f11.z));
                v.w = f2bf(0.5625f * b2f(f00.w) + 0.1875f * (b2f(f01.w) + b2f(f10.w)) + 0.0625f * b2f(f11.w));
            }
            *(ushort4*)&xlds[px * 72 + c4] = v;
        }
    } else {
        for (int i = tid; i < 800; i += 256) {
            int px = i >> 3, c8 = (i & 7) * 8;
            int yy = px / 10, xx = px - yy * 10;
            int gy = y0 - 1 + yy, gx = x0 - 1 + xx;
            uint4 v = {0, 0, 0, 0};
            if (gy >= 0 && gy < H && gx >= 0 && gx < H)
                v = *(const uint4*)&in[((gy * H + gx) << 6) + c8];
            *(uint4*)&xlds[px * 72 + c8] = v;
        }
    }
    __syncthreads();

    f32x4 acc[4];
#pragma unroll
    for (int m = 0; m < 4; ++m) acc[m] = (f32x4){0.f, 0.f, 0.f, 0.f};
    const bhalf8* wp8 = (const bhalf8*)wp;
    int sy = 2 * w + (n >> 3), sx = n & 7;

    bhalf8 a0 = wp8[0 * 64 + lane];
    bhalf8 a1 = wp8[1 * 64 + lane];
    bhalf8 a2 = wp8[2 * 64 + lane];
    bhalf8 a3 = wp8[3 * 64 + lane];
    bhalf8 bb = *(const bhalf8*)&xlds[(sy * 10 + sx) * 72 + q * 8];

#pragma unroll 1
    for (int p = 0; p < 18; ++p) {
        bhalf8 na0, na1, na2, na3, nbb;
        if (p < 17) {
            int pn = p + 1;
            na0 = wp8[(pn * 4 + 0) * 64 + lane];
            na1 = wp8[(pn * 4 + 1) * 64 + lane];
            na2 = wp8[(pn * 4 + 2) * 64 + lane];
            na3 = wp8[(pn * 4 + 3) * 64 + lane];
            int tap = pn >> 1, ch = pn & 1;
            int dy = tap / 3, dx = tap - dy * 3;
            nbb = *(const bhalf8*)&xlds[((sy + dy) * 10 + sx + dx) * 72 + ch * 32 + q * 8];
        }
        acc[0] = __builtin_amdgcn_mfma_f32_16x16x32_bf16(a0, bb, acc[0], 0, 0, 0);
        acc[1] = __builtin_amdgcn_mfma_f32_16x16x32_bf16(a1, bb, acc[1], 0, 0, 0);
        acc[2] = __builtin_amdgcn_mfma_f32_16x16x32_bf16(a2, bb, acc[2], 0, 0, 0);
        acc[3] = __builtin_amdgcn_mfma_f32_16x16x32_bf16(a3, bb, acc[3], 0, 0, 0);
        a0 = na0; a1 = na1; a2 = na2; a3 = na3; bb = nbb;
    }

    int gy = y0 + sy, gx = x0 + sx;
    if (gy < H && gx < H) {
        int base = (gy * H + gx) << 6;
#pragma unroll
        for (int m = 0; m < 4; ++m) {
            int oc0 = m * 16 + q * 4;
            float v0 = acc[m][0], v1 = acc[m][1], v2 = acc[m][2], v3 = acc[m][3];
            if (bev) {
                float4 av = *(const float4*)&bev[base + oc0];
                v0 += av.x; v1 += av.y; v2 += av.z; v3 += av.w;
            }
            ushort4 o = { f2bf(v0), f2bf(v1), f2bf(v2), f2bf(v3) };
            chstore4(&outb[base + oc0], o);
        }
    }

    if (dostats) {
#pragma unroll
        for (int m = 0; m < 4; ++m)
#pragma unroll
            for (int r = 0; r < 4; ++r) {
                float v = acc[m][r];
                float s = v, s2 = v * v;
#pragma unroll
                for (int d = 1; d < 16; d <<= 1) {
                    s += __shfl_xor(s, d, 64);
                    s2 += __shfl_xor(s2, d, 64);
                }
                if (n == 0) {
                    int oc = m * 16 + q * 4 + r;
                    red[w * 128 + oc] = s;
                    red[w * 128 + 64 + oc] = s2;
                }
            }
        __syncthreads();
        if (tid < 128) {
            float t = red[tid] + red[128 + tid] + red[256 + tid] + red[384 + tid];
            atomicAdd(&sacc[tid], t);
        }
    }
}

// ---------------------------------------------------------------------------
// FUSED basic block: out = relu(x + conv2(relu(conv1(x)))). Cached loads,
// coherent stores. nrm: x = instnorm(in)+nskip at staging. final_: f32 NCHW.
// ---------------------------------------------------------------------------
__device__ __forceinline__ void bb_tile(
    int bx, int H, const u16* __restrict__ in,
    const u16* __restrict__ wp1, const u16* __restrict__ wp2,
    u16* __restrict__ outb, float* __restrict__ outf, int final_,
    int nrm, const u16* __restrict__ nskip, const float* __restrict__ sraw,
    char* smem)
{
    u16* xin  = (u16*)smem;              // 144*72*2 = 20736 B
    u16* ilds = (u16*)(smem + 20736);    // 100*72*2 = 14400 B
    float* nm = (float*)(smem + 35136);  // 64
    float* nr = nm + 64;                 // 64

    int tid = threadIdx.x;
    int gw = (H + 7) >> 3;
    int by = bx / gw, bxx = bx - by * gw;
    int y0 = by * 8, x0 = bxx * 8;
    int w = tid >> 6, lane = tid & 63;
    int n = lane & 15, q = lane >> 4;

    if (nrm) {
        if (tid < 64) {
            float s = cload(&sraw[tid]), s2 = cload(&sraw[64 + tid]);
            float mean = s * (1.f / 40000.f);
            float var = s2 * (1.f / 40000.f) - mean * mean;
            nm[tid] = mean;
            nr[tid] = rsqrtf(var + 1e-5f);
        }
        __syncthreads();
        for (int i = tid; i < 2304; i += 256) {
            int px = i >> 4, c4 = (i & 15) * 4;
            int yy = px / 12, xx = px - yy * 12;
            int gy = y0 - 2 + yy, gx = x0 - 2 + xx;
            ushort4 v = {0, 0, 0, 0};
            if (gy >= 0 && gy < H && gx >= 0 && gx < H) {
                int off = ((gy * H + gx) << 6) + c4;
                ushort4 a = *(const ushort4*)&in[off];
                ushort4 b = *(const ushort4*)&nskip[off];
                v.x = f2bf((b2f(a.x) - nm[c4 + 0]) * nr[c4 + 0] + b2f(b.x));
                v.y = f2bf((b2f(a.y) - nm[c4 + 1]) * nr[c4 + 1] + b2f(b.y));
                v.z = f2bf((b2f(a.z) - nm[c4 + 2]) * nr[c4 + 2] + b2f(b.z));
                v.w = f2bf((b2f(a.w) - nm[c4 + 3]) * nr[c4 + 3] + b2f(b.w));
            }
            *(ushort4*)&xin[px * 72 + c4] = v;
        }
    } else {
        for (int i = tid; i < 1152; i += 256) {
            int px = i >> 3, c8 = (i & 7) * 8;
            int yy = px / 12, xx = px - yy * 12;
            int gy = y0 - 2 + yy, gx = x0 - 2 + xx;
            uint4 v = {0, 0, 0, 0};
            if (gy >= 0 && gy < H && gx >= 0 && gx < H)
                v = *(const uint4*)&in[((gy * H + gx) << 6) + c8];
            *(uint4*)&xin[px * 72 + c8] = v;
        }
    }
    __syncthreads();

    const bhalf8* w1 = (const bhalf8*)wp1;
#pragma unroll 1
    for (int r = 0; r < 2; ++r) {
        int t = w + 4 * r;
        int px = t * 16 + n;
        bool val = px < 100;
        int pc = val ? px : 0;
        int yy = pc / 10, xx = pc - yy * 10;

        f32x4 acc[4];
#pragma unroll
        for (int m = 0; m < 4; ++m) acc[m] = (f32x4){0.f, 0.f, 0.f, 0.f};

        bhalf8 a0 = w1[0 * 64 + lane];
        bhalf8 a1 = w1[1 * 64 + lane];
        bhalf8 a2 = w1[2 * 64 + lane];
        bhalf8 a3 = w1[3 * 64 + lane];
        bhalf8 bb = *(const bhalf8*)&xin[(yy * 12 + xx) * 72 + q * 8];

#pragma unroll 1
        for (int p = 0; p < 18; ++p) {
            bhalf8 na0, na1, na2, na3, nbb;
            if (p < 17) {
                int pn = p + 1;
                na0 = w1[(pn * 4 + 0) * 64 + lane];
                na1 = w1[(pn * 4 + 1) * 64 + lane];
                na2 = w1[(pn * 4 + 2) * 64 + lane];
                na3 = w1[(pn * 4 + 3) * 64 + lane];
                int tap = pn >> 1, ch = pn & 1;
                int dy = tap / 3, dx = tap - dy * 3;
                nbb = *(const bhalf8*)&xin[((yy + dy) * 12 + xx + dx) * 72 + ch * 32 + q * 8];
            }
            acc[0] = __builtin_amdgcn_mfma_f32_16x16x32_bf16(a0, bb, acc[0], 0, 0, 0);
            acc[1] = __builtin_amdgcn_mfma_f32_16x16x32_bf16(a1, bb, acc[1], 0, 0, 0);
            acc[2] = __builtin_amdgcn_mfma_f32_16x16x32_bf16(a2, bb, acc[2], 0, 0, 0);
            acc[3] = __builtin_amdgcn_mfma_f32_16x16x32_bf16(a3, bb, acc[3], 0, 0, 0);
            a0 = na0; a1 = na1; a2 = na2; a3 = na3; bb = nbb;
        }

        int iy = y0 - 1 + yy, ix = x0 - 1 + xx;
        bool ok = val && iy >= 0 && iy < H && ix >= 0 && ix < H;
        if (val) {
#pragma unroll
            for (int m = 0; m < 4; ++m) {
                ushort4 o = {0, 0, 0, 0};
                if (ok) {
                    o.x = f2bf(fmaxf(acc[m][0], 0.f));
                    o.y = f2bf(fmaxf(acc[m][1], 0.f));
                    o.z = f2bf(fmaxf(acc[m][2], 0.f));
                    o.w = f2bf(fmaxf(acc[m][3], 0.f));
                }
                *(ushort4*)&ilds[px * 72 + m * 16 + q * 4] = o;
            }
        }
    }
    __syncthreads();

    f32x4 acc[4];
#pragma unroll
    for (int m = 0; m < 4; ++m) acc[m] = (f32x4){0.f, 0.f, 0.f, 0.f};
    const bhalf8* w2 = (const bhalf8*)wp2;
    int sy = 2 * w + (n >> 3), sx = n & 7;

    bhalf8 a0 = w2[0 * 64 + lane];
    bhalf8 a1 = w2[1 * 64 + lane];
    bhalf8 a2 = w2[2 * 64 + lane];
    bhalf8 a3 = w2[3 * 64 + lane];
    bhalf8 bb = *(const bhalf8*)&ilds[(sy * 10 + sx) * 72 + q * 8];

#pragma unroll 1
    for (int p = 0; p < 18; ++p) {
        bhalf8 na0, na1, na2, na3, nbb;
        if (p < 17) {
            int pn = p + 1;
            na0 = w2[(pn * 4 + 0) * 64 + lane];
            na1 = w2[(pn * 4 + 1) * 64 + lane];
            na2 = w2[(pn * 4 + 2) * 64 + lane];
            na3 = w2[(pn * 4 + 3) * 64 + lane];
            int tap = pn >> 1, ch = pn & 1;
            int dy = tap / 3, dx = tap - dy * 3;
            nbb = *(const bhalf8*)&ilds[((sy + dy) * 10 + sx + dx) * 72 + ch * 32 + q * 8];
        }
        acc[0] = __builtin_amdgcn_mfma_f32_16x16x32_bf16(a0, bb, acc[0], 0, 0, 0);
        acc[1] = __builtin_amdgcn_mfma_f32_16x16x32_bf16(a1, bb, acc[1], 0, 0, 0);
        acc[2] = __builtin_amdgcn_mfma_f32_16x16x32_bf16(a2, bb, acc[2], 0, 0, 0);
        acc[3] = __builtin_amdgcn_mfma_f32_16x16x32_bf16(a3, bb, acc[3], 0, 0, 0);
        a0 = na0; a1 = na1; a2 = na2; a3 = na3; bb = nbb;
    }

    int gy = y0 + sy, gx = x0 + sx;
    if (gy < H && gx < H) {
        int base = (gy * H + gx) << 6;
#pragma unroll
        for (int m = 0; m < 4; ++m) {
            int oc0 = m * 16 + q * 4;
            ushort4 xr = *(const ushort4*)&xin[((sy + 2) * 12 + sx + 2) * 72 + oc0];
            float v0 = fmaxf(acc[m][0] + b2f(xr.x), 0.f);
            float v1 = fmaxf(acc[m][1] + b2f(xr.y), 0.f);
            float v2 = fmaxf(acc[m][2] + b2f(xr.z), 0.f);
            float v3 = fmaxf(acc[m][3] + b2f(xr.w), 0.f);
            if (final_) {
                int pix = gy * H + gx;
                outf[(oc0 + 0) * H * H + pix] = v0;
                outf[(oc0 + 1) * H * H + pix] = v1;
                outf[(oc0 + 2) * H * H + pix] = v2;
                outf[(oc0 + 3) * H * H + pix] = v3;
            } else {
                ushort4 o = { f2bf(v0), f2bf(v1), f2bf(v2), f2bf(v3) };
                chstore4(&outb[base + oc0], o);
            }
        }
    }
}

// ---------------------------------------------------------------------------
// Persistent megakernel: 8 phases, 7 grid barriers.
// ---------------------------------------------------------------------------
__global__ __launch_bounds__(256, 4) void gls_mega(
    const float* __restrict__ feats, const float* __restrict__ bev_emb,
    const float* __restrict__ conv1_w, const float* __restrict__ blk_w,
    const float* __restrict__ up_w, const float* __restrict__ means,
    const float* __restrict__ cov6, const float* __restrict__ opac,
    u16* __restrict__ wprep, float* __restrict__ params, int* __restrict__ cnts,
    u16* __restrict__ R0h, u16* __restrict__ X0h,
    u16* __restrict__ X1h, u16* __restrict__ X2h,
    u16* __restrict__ Qr0h, u16* __restrict__ Sh,
    u16* __restrict__ Uh, u16* __restrict__ Y1h,
    float* __restrict__ out, int* __restrict__ barmem, float* __restrict__ sacc)
{
    __shared__ __align__(16) char smem[36352];
    int bid = blockIdx.x;
    int tid = threadIdx.x;
    int* leaf = barmem;
    int* root = barmem + 512;
    int* flag = barmem + 513;
    int ph = 0;

    // ---- P0: parallel splat precompute, no compaction (16 blocks) ----
    if (bid < 16) {
        int item = bid * 256 + tid;          // 0..4095
        int s = item >> 11, g = item & 2047;
        float mx = means[g * 3 + 0], my = means[g * 3 + 1], mz = means[g * 3 + 2];
        float op = opac[g * 2 + s];
        bool mask = (mx >= -50.f && mx <= 50.f && my >= -50.f && my <= 50.f &&
                     mz >= -4.f && mz <= 4.f && op > 0.05f);
        float Hs = (float)(100 << s), sh = (float)(1 << s);
        float u = 0.f, v = 0.f, A = 0.f, B = 0.f, C = 0.f, pthr = 0.f;
        float rx = -1.f, ry = -1.f;          // sentinel: bbox test always fails
        if (mask) {
            u = -sh * my + 0.5f * Hs;
            v = -sh * mx + 0.5f * Hs;
            float a = sh * sh * cov6[g * 6 + 3] + 0.3f;
            float c = sh * sh * cov6[g * 6 + 0] + 0.3f;
            float bb = sh * sh * cov6[g * 6 + 1];
            float det = fmaxf(a * c - bb * bb, 1e-8f);
            float t = logf(255.f * op);
            A = c / det; B = -bb / det; C = a / det;
            pthr = -t;
            rx = sqrtf(2.f * t * a); ry = sqrtf(2.f * t * c);
        }
        float* Q = params + (s * G_N + g) * PSTR;
        cstore8(&Q[0], u, v);
        cstore8(&Q[2], A, B);
        cstore8(&Q[4], C, op);
        cstore8(&Q[6], pthr, __int_as_float(g));
        cstore8(&Q[8], rx, ry);
        unsigned long long bal = __ballot(mask);
        if ((tid & 63) == 0) atomicAdd(&cnts[s], __popcll(bal));
    }
    gbar(leaf, root, flag, ++ph);

    // ---- P1: render (0..793) || weight repack (794..991) ----
    if (bid < 794) {
        render_tile(bid, params, feats, R0h, Qr0h, smem);
    } else if (bid < 992) {
        int rb = bid - 794;
        int p = rb % 18, c = rb / 18;
        const float* src;
        if (c == 0) src = conv1_w;
        else if (c <= 4) src = blk_w + (c - 1) * WC;
        else if (c == 5) src = conv1_w + WC;
        else if (c == 6) src = up_w;
        else src = blk_w + (c - 3) * WC;
        int tap = p >> 1;
        int m = tid >> 6, lane = tid & 63;
        int oc = m * 16 + (lane & 15);
        int ci0 = (p & 1) * 32 + (lane >> 4) * 8;
        u16 v[8];
#pragma unroll
        for (int j = 0; j < 8; ++j)
            v[j] = f2bf(src[(oc * 64 + ci0 + j) * 9 + tap]);
        u16* dst = wprep + ((c * 18 + p) * 4 + m) * 64 * 8 + lane * 8;
        chstore4(dst, (ushort4){v[0], v[1], v[2], v[3]});
        chstore4(dst + 4, (ushort4){v[4], v[5], v[6], v[7]});
    }
    gbar(leaf, root, flag, ++ph);

    // ---- P2: c0 (H100, +bev_emb) ----
    if (bid < 169)
        conv_tile(bid, 100, R0h, wprep + 0 * WC, bev_emb, X0h, 0, 0, nullptr, smem);
    gbar(leaf, root, flag, ++ph);

    // ---- P3: bb1 (H100) || c5 tiles 0..311 ----
    if (bid < 169)
        bb_tile(bid, 100, X0h, wprep + 1 * WC, wprep + 2 * WC, X1h,
                nullptr, 0, 0, nullptr, nullptr, smem);
    else if (bid < 481)
        conv_tile(bid - 169, 200, Qr0h, wprep + 5 * WC, nullptr, Sh, 0, 0, nullptr, smem);
    gbar(leaf, root, flag, ++ph);

    // ---- P4: bb2 (H100) || c5 tiles 312..624 ----
    if (bid < 169)
        bb_tile(bid, 100, X1h, wprep + 3 * WC, wprep + 4 * WC, X2h,
                nullptr, 0, 0, nullptr, nullptr, smem);
    else if (bid < 482)
        conv_tile(312 + bid - 169, 200, Qr0h, wprep + 5 * WC, nullptr, Sh, 0, 0, nullptr, smem);
    gbar(leaf, root, flag, ++ph);

    // ---- P5: upconv (LDS bilinear) + instance-norm stats ----
    if (bid < 625)
        conv_tile(bid, 200, X2h, wprep + 6 * WC, nullptr, Uh, 1, 1, sacc, smem);
    gbar(leaf, root, flag, ++ph);

    // ---- P6: fused bb with instance-norm + skip staging ----
    if (bid < 625)
        bb_tile(bid, 200, Uh, wprep + 7 * WC, wprep + 8 * WC, Y1h,
                nullptr, 0, 1, Sh, sacc, smem);
    gbar(leaf, root, flag, ++ph);

    // ---- P7: fused bb, final epilogue writes d_out (f32 NCHW) ----
    if (bid == 0 && threadIdx.x == 0)
        out[2560000] = (float)(iload(&cnts[0]) + iload(&cnts[1]));
    if (bid < 625)
        bb_tile(bid, 200, Y1h, wprep + 9 * WC, wprep + 10 * WC, nullptr,
                out, 1, 0, nullptr, nullptr, smem);
}

// ---------------------------------------------------------------------------
extern "C" void kernel_launch(void* const* d_in, const int* in_sizes, int n_in,
                              void* d_out, int out_size, void* d_ws, size_t ws_size,
                              hipStream_t stream)
{
    const float* feats   = (const float*)d_in[0];
    const float* means   = (const float*)d_in[1];
    const float* cov6    = (const float*)d_in[2];
    const float* opac    = (const float*)d_in[3];
    const float* bev_emb = (const float*)d_in[4];
    const float* conv1_w = (const float*)d_in[5];
    const float* blk_w   = (const float*)d_in[6];
    const float* up_w    = (const float*)d_in[7];
    float* out = (float*)d_out;
    float* ws = (float*)d_ws;

    float* P      = ws;                          // 49152 floats
    int*   cnts   = (int*)(ws + 49152);          // 2 ints
    int*   barmem = (int*)(ws + 49280);          // 520 ints
    float* sacc   = ws + 49856;                  // 128 floats -> ends 49984
    u16*   wprep  = (u16*)(ws + 50176);          // 11*36864 u16

    u16* R0h  = (u16*)(ws + 262144);             // H100 bf16 HWC
    u16* X0h  = (u16*)(ws + 589824);
    u16* X1h  = (u16*)(ws + 917504);
    u16* X2h  = (u16*)(ws + 1245184);
    u16* Qr0h = (u16*)(ws + 1572864);            // H200 bf16 HWC
    u16* Sh   = (u16*)(ws + 2883584);
    u16* Uh   = (u16*)(ws + 4194304);
    u16* Y1h  = (u16*)(ws + 5505024);

    // zero cnts + barrier counters + stats accumulators (graph-safe)
    hipMemsetAsync(cnts, 0, (49984 - 49152) * 4, stream);
    gls_mega<<<NBLK, 256, 0, stream>>>(feats, bev_emb, conv1_w, blk_w, up_w,
                                       means, cov6, opac, wprep, P, cnts,
                                       R0h, X0h, X1h, X2h, Qr0h, Sh, Uh, Y1h,
                                       out, barmem, sacc);
    (void)in_sizes; (void)n_in; (void)out_size; (void)ws_size;
}